// Round 7
// baseline (718.677 us; speedup 1.0000x reference)
//
#include <hip/hip_runtime.h>
#include <hip/hip_bf16.h>
#include <cstdint>
#include <cstddef>

// Problem dims (fixed)
#define BATCH 2
#define TLEN  2048
#define NHEAD 8
#define HD    128
#define HIDN  1024
#define MTOT  4096          // BATCH*TLEN
#define MAT_ELEMS 1048576   // 1024*1024
#define XELEMS 4194304      // 4096*1024
#define SCAN_C 32
#define NCH    64           // TLEN / SCAN_C
#define SSC  1024.0f
#define ISSC 0.0009765625f

typedef _Float16 f16;
typedef _Float16 f16x2 __attribute__((ext_vector_type(2)));
typedef _Float16 f16x8 __attribute__((ext_vector_type(8)));
typedef float    f32x4 __attribute__((ext_vector_type(4)));

__device__ __forceinline__ float sigmoidf_(float v) { return 1.0f / (1.0f + __expf(-v)); }

// f16x2 dot with f32 accumulate: v_dot2_f32_f16 (exact products, f32 accum)
__device__ __forceinline__ float fdot2_(f16x2 a, f16x2 b, float c)
{
#if __has_builtin(__builtin_amdgcn_fdot2)
    return __builtin_amdgcn_fdot2(a, b, c, false);
#else
    return fmaf((float)a.x, (float)b.x, fmaf((float)a.y, (float)b.y, c));
#endif
}

// async global->LDS DMA: 16B per lane, LDS dest = wave-uniform base + lane*16B
__device__ __forceinline__ void gload_lds16(const f16* g, f16* l)
{
    __builtin_amdgcn_global_load_lds(
        (const __attribute__((address_space(1))) uint32_t*)(g),
        (__attribute__((address_space(3))) uint32_t*)(l), 16, 0, 0);
}

// ---------------------------------------------------------------------------
// K0: convert x (fp32) -> f16
__global__ __launch_bounds__(256) void convert_x_kernel(const float* __restrict__ x,
                                                        f16* __restrict__ x16)
{
    int i = (blockIdx.x * 256 + threadIdx.x) * 4;
    float4 v = *(const float4*)(x + i);
    union { f16 h[4]; uint2 u; } pk;
    pk.h[0] = (f16)v.x; pk.h[1] = (f16)v.y; pk.h[2] = (f16)v.z; pk.h[3] = (f16)v.w;
    *(uint2*)(x16 + i) = pk.u;
}

// ---------------------------------------------------------------------------
// K1: transpose-convert the six 1024x1024 weight matrices to f16 WT[mat][n][k]
__global__ __launch_bounds__(256) void transpose_convert_kernel(
    const float* __restrict__ Wq, const float* __restrict__ Wk, const float* __restrict__ Wv,
    const float* __restrict__ Wa, const float* __restrict__ Wg, const float* __restrict__ Wo,
    f16* __restrict__ WT)
{
    __shared__ float tile[32][33];
    int mat = blockIdx.z;
    const float* W = (mat == 0) ? Wq : (mat == 1) ? Wk : (mat == 2) ? Wv
                   : (mat == 3) ? Wa : (mat == 4) ? Wg : Wo;
    int k0 = blockIdx.y * 32, n0 = blockIdx.x * 32;
    int tr = threadIdx.x >> 3;
    int tc = (threadIdx.x & 7) * 4;
    float4 vin = *(const float4*)(W + (size_t)(k0 + tr) * HIDN + n0 + tc);
    tile[tr][tc + 0] = vin.x; tile[tr][tc + 1] = vin.y;
    tile[tr][tc + 2] = vin.z; tile[tr][tc + 3] = vin.w;
    __syncthreads();
    f16* dst = WT + (size_t)(mat * HIDN + n0 + tr) * HIDN + k0 + tc;
    union { f16 h[4]; uint2 u; } pk;
    pk.h[0] = (f16)tile[tc + 0][tr]; pk.h[1] = (f16)tile[tc + 1][tr];
    pk.h[2] = (f16)tile[tc + 2][tr]; pk.h[3] = (f16)tile[tc + 3][tr];
    *(uint2*)dst = pk.u;
}

// ---------------------------------------------------------------------------
// K2/K7: f16 MFMA GEMM, C = A[M,1024] @ BT[n][k]^T, 128x128 tile, BK=32.
// m97 structure: global_load_lds width=16 staging into linear [128][32] tiles.
template <int MODE>
__global__ __launch_bounds__(256) void gemm_f16(
    const f16* __restrict__ A, const f16* __restrict__ BT,
    float* __restrict__ out_f32,
    f16* __restrict__ qkv_hat, float* __restrict__ a_buf, f16* __restrict__ g16,
    const float* __restrict__ ba)
{
    __shared__ __align__(16) f16 As[128][32];
    __shared__ __align__(16) f16 Bs[128][32];
    int m0 = blockIdx.y * 128;
    int n0 = blockIdx.x * 128;
    int tid = threadIdx.x;
    int w = tid >> 6, lane = tid & 63;
    int L16 = lane & 15, quad = lane >> 4;
    int wm = (w >> 1) * 64, wn = (w & 1) * 64;

    f32x4 acc[4][4];
#pragma unroll
    for (int i = 0; i < 4; ++i)
#pragma unroll
        for (int j = 0; j < 4; ++j) acc[i][j] = (f32x4){0.f, 0.f, 0.f, 0.f};

    int ldr = tid >> 2;            // 0..63
    int ldc = (tid & 3) * 8;
    f16* asb0 = &As[0][0]  + w * 512;
    f16* asb1 = &As[64][0] + w * 512;
    f16* bsb0 = &Bs[0][0]  + w * 512;
    f16* bsb1 = &Bs[64][0] + w * 512;

    for (int k0 = 0; k0 < 1024; k0 += 32) {
        __syncthreads();
        gload_lds16(A  + (size_t)(m0 + ldr) * HIDN + k0 + ldc,      asb0);
        gload_lds16(A  + (size_t)(m0 + ldr + 64) * HIDN + k0 + ldc, asb1);
        gload_lds16(BT + (size_t)(n0 + ldr) * HIDN + k0 + ldc,      bsb0);
        gload_lds16(BT + (size_t)(n0 + ldr + 64) * HIDN + k0 + ldc, bsb1);
        __syncthreads();
        f16x8 af[4], bf[4];
#pragma unroll
        for (int i = 0; i < 4; ++i) {
            af[i] = *(const f16x8*)(&As[wm + i * 16 + L16][quad * 8]);
            bf[i] = *(const f16x8*)(&Bs[wn + i * 16 + L16][quad * 8]);
        }
#pragma unroll
        for (int i = 0; i < 4; ++i)
#pragma unroll
            for (int j = 0; j < 4; ++j)
                acc[i][j] = __builtin_amdgcn_mfma_f32_16x16x32_f16(af[i], bf[j], acc[i][j], 0, 0, 0);
    }

#pragma unroll
    for (int i = 0; i < 4; ++i) {
#pragma unroll
        for (int j = 0; j < 4; ++j) {
            f32x4 c = acc[i][j];
            int mbase = m0 + wm + i * 16 + quad * 4;
            int n = n0 + wn + j * 16 + L16;
            if (MODE == 1) {
#pragma unroll
                for (int r = 0; r < 4; ++r)
                    out_f32[(size_t)(mbase + r) * HIDN + n] = c[r];
            } else {
                int mat = n >> 10;
                int nn = n & 1023;
                if (mat < 3) {
#pragma unroll
                    for (int r = 0; r < 4; ++r)
                        qkv_hat[(size_t)mat * XELEMS + (size_t)(mbase + r) * HIDN + nn] = (f16)c[r];
                } else if (mat == 3) {
                    float bav = ba[nn];
#pragma unroll
                    for (int r = 0; r < 4; ++r)
                        a_buf[(size_t)(mbase + r) * HIDN + nn] = sigmoidf_(c[r] + bav);
                } else {
#pragma unroll
                    for (int r = 0; r < 4; ++r)
                        g16[(size_t)(mbase + r) * HIDN + nn] = (f16)sigmoidf_(c[r]);
                }
            }
        }
    }
}

// ---------------------------------------------------------------------------
// K3: beta = sigmoid(x @ Wb + bb), fp32 exact path.
__global__ __launch_bounds__(256) void beta_kernel(const float* __restrict__ x,
                                                   const float* __restrict__ Wb,
                                                   const float* __restrict__ bb,
                                                   float* __restrict__ beta_buf)
{
    int row = blockIdx.x;
    int h = threadIdx.x >> 5, lane = threadIdx.x & 31;
    const float* xr = x + (size_t)row * HIDN;
    float part = 0.f;
    for (int i = lane; i < HIDN; i += 32)
        part += xr[i] * Wb[i * NHEAD + h];
#pragma unroll
    for (int m = 1; m <= 16; m <<= 1) part += __shfl_xor(part, m);
    if (lane == 0)
        beta_buf[(size_t)row * NHEAD + h] = sigmoidf_(part + bb[h]);
}

// ---------------------------------------------------------------------------
// K4: causal depthwise conv (K=4) + SiLU (+ scale for k), f16 output.
__global__ __launch_bounds__(256) void conv_silu_kernel(
    const f16* __restrict__ qkv_hat,
    const float* __restrict__ cqw, const float* __restrict__ cqb,
    const float* __restrict__ ckw, const float* __restrict__ ckb,
    const float* __restrict__ cvw, const float* __restrict__ cvb,
    f16* __restrict__ qkv16)
{
    int z = blockIdx.y;
    int row = blockIdx.x;
    int tloc = row & (TLEN - 1);
    int c4 = threadIdx.x * 4;
    const f16* src = qkv_hat + (size_t)z * XELEMS;
    const float* w  = (z == 0) ? cqw : (z == 1) ? ckw : cvw;
    const float* bi = (z == 0) ? cqb : (z == 1) ? ckb : cvb;

    float xv[4][4];
#pragma unroll
    for (int j = 0; j < 4; ++j) {
        int tt = tloc - 3 + j;
        if (tt >= 0) {
            const f16* p = src + (size_t)(row - 3 + j) * HIDN + c4;
            xv[j][0] = (float)p[0]; xv[j][1] = (float)p[1];
            xv[j][2] = (float)p[2]; xv[j][3] = (float)p[3];
        } else {
            xv[j][0] = xv[j][1] = xv[j][2] = xv[j][3] = 0.f;
        }
    }
    float scale = (z == 1) ? 0.08838834764831845f : 1.0f;  // 128^-0.5 for k
    union { f16 h[4]; uint2 u; } pk;
#pragma unroll
    for (int cc = 0; cc < 4; ++cc) {
        float4 wc = *(const float4*)(w + (size_t)(c4 + cc) * 4);
        float acc = bi[c4 + cc] + wc.x * xv[0][cc] + wc.y * xv[1][cc]
                                 + wc.z * xv[2][cc] + wc.w * xv[3][cc];
        pk.h[cc] = (f16)(acc * sigmoidf_(acc) * scale);
    }
    *(uint2*)(qkv16 + (size_t)z * XELEMS + (size_t)row * HIDN + c4) = pk.u;
}

// ---------------------------------------------------------------------------
// K4b: gram pre-pass. Per (chunk, bh): all state-INDEPENDENT chunk matrices.
__global__ __launch_bounds__(64) void gram_kernel(
    const f16* __restrict__ q16, const f16* __restrict__ k16,
    f16* __restrict__ G_g, f16* __restrict__ KQ_g,
    f16* __restrict__ Gx_g, f16* __restrict__ Qx_g, f16* __restrict__ KT_g)
{
    int ch = blockIdx.x;
    int bh = blockIdx.y;
    int b = bh >> 3, h = bh & 7;
    int lane = threadIdx.x;
    int L16 = lane & 15, quad = lane >> 4;
    size_t rowbase = (size_t)(b * TLEN) * HIDN + h * HD;
    int t0 = ch * SCAN_C;
    bool hasNext = (ch + 1 < NCH);

    union ZU { uint4 u; f16x8 v; };
    ZU zz; zz.u = (uint4){0, 0, 0, 0};

    f16x8 kc[2][4], qc[2][4], kn[2][4], qn[2][4];
#pragma unroll
    for (int nt = 0; nt < 2; ++nt)
#pragma unroll
        for (int kk = 0; kk < 4; ++kk) {
            size_t g = rowbase + (size_t)(t0 + nt * 16 + L16) * HIDN + kk * 32 + quad * 8;
            kc[nt][kk] = *(const f16x8*)(k16 + g);
            qc[nt][kk] = *(const f16x8*)(q16 + g);
            if (hasNext) {
                kn[nt][kk] = *(const f16x8*)(k16 + g + (size_t)SCAN_C * HIDN);
                qn[nt][kk] = *(const f16x8*)(q16 + g + (size_t)SCAN_C * HIDN);
            } else {
                kn[nt][kk] = zz.v; qn[nt][kk] = zz.v;
            }
        }

    f32x4 aG[2][2], aKQ[2][2], aGx[2][2], aQx[2][2];
#pragma unroll
    for (int i = 0; i < 2; ++i)
#pragma unroll
        for (int j = 0; j < 2; ++j) {
            aG[i][j] = (f32x4){0, 0, 0, 0}; aKQ[i][j] = (f32x4){0, 0, 0, 0};
            aGx[i][j] = (f32x4){0, 0, 0, 0}; aQx[i][j] = (f32x4){0, 0, 0, 0};
        }
#pragma unroll
    for (int kk = 0; kk < 4; ++kk)
#pragma unroll
        for (int mt = 0; mt < 2; ++mt)
#pragma unroll
            for (int nt = 0; nt < 2; ++nt) {
                aG[mt][nt]  = __builtin_amdgcn_mfma_f32_16x16x32_f16(kc[mt][kk], kc[nt][kk], aG[mt][nt], 0, 0, 0);
                aKQ[mt][nt] = __builtin_amdgcn_mfma_f32_16x16x32_f16(kc[mt][kk], qc[nt][kk], aKQ[mt][nt], 0, 0, 0);
                aGx[mt][nt] = __builtin_amdgcn_mfma_f32_16x16x32_f16(kc[mt][kk], kn[nt][kk], aGx[mt][nt], 0, 0, 0);
                aQx[mt][nt] = __builtin_amdgcn_mfma_f32_16x16x32_f16(kc[mt][kk], qn[nt][kk], aQx[mt][nt], 0, 0, 0);
            }

    size_t gb = ((size_t)bh * NCH + ch) * 1024;
#pragma unroll
    for (int nt = 0; nt < 2; ++nt) {
        int t = nt * 16 + L16;
#pragma unroll
        for (int mt = 0; mt < 2; ++mt) {
            union { f16 e[4]; uint2 u2; } pg, pq, px, py;
#pragma unroll
            for (int r = 0; r < 4; ++r) {
                pg.e[r] = (f16)aG[mt][nt][r];
                pq.e[r] = (f16)aKQ[mt][nt][r];
                px.e[r] = (f16)aGx[mt][nt][r];
                py.e[r] = (f16)aQx[mt][nt][r];
            }
            *(uint2*)(G_g  + gb + t * 32 + mt * 16 + quad * 4) = pg.u2;
            *(uint2*)(KQ_g + gb + t * 32 + mt * 16 + quad * 4) = pq.u2;
            *(uint2*)(Gx_g + gb + t * 32 + mt * 16 + quad * 4) = px.u2;
            *(uint2*)(Qx_g + gb + t * 32 + mt * 16 + quad * 4) = py.u2;
        }
    }
    // K^T store (scalar f16, off critical path of the serial scan)
    size_t kb = ((size_t)bh * NCH + ch) * 4096;
#pragma unroll
    for (int nt = 0; nt < 2; ++nt) {
        int t = nt * 16 + L16;
#pragma unroll
        for (int kk = 0; kk < 4; ++kk)
#pragma unroll
            for (int j = 0; j < 8; ++j) {
                int k = kk * 32 + quad * 8 + j;
                KT_g[kb + (size_t)k * 32 + t] = kc[nt][kk][j];
            }
    }
}

// ---------------------------------------------------------------------------
// K5: 4-pipeline TLP scan. Each 512-thread block runs FOUR independent
//  (bh, v-slice) producer/consumer pipelines (w0=solve, w1=state keeper),
//  8 waves/block = 2 waves/SIMD so stalls in one pipeline are filled by the
//  other pipeline sharing the SIMD. Per-pipeline dataflow is bit-identical
//  to the R3/R6 2-wave kernel; only residency moved:
//   - fp32 master state Sp -> w1 registers (8 x f32x4)
//   - KT fragments read directly from global KT_g (same bytes as old LDS copy)
//   - Gx/Qx fixup fragments register-prefetched by w0 one chunk ahead
__global__ __launch_bounds__(512, 2) void scan2_kernel(
    const f16* __restrict__ q16, const f16* __restrict__ k16, const f16* __restrict__ v16,
    const float* __restrict__ a_buf, const float* __restrict__ beta_buf,
    const f16* __restrict__ G_g, const f16* __restrict__ KQ_g,
    const f16* __restrict__ Gx_g, const f16* __restrict__ Qx_g, const f16* __restrict__ KT_g,
    float* __restrict__ o_buf)
{
    __shared__ __align__(16) f16   Sp16_a[4][16 * 136];   // f16 state shadow
    __shared__ __align__(16) f16   G_a[4][2][1024];       // G[t*32+tau]
    __shared__ __align__(16) f16   Q_a[4][2][1024];       // KQ[t*32+tau]
    __shared__ __align__(16) float skv_a[4][2][16 * 34];
    __shared__ __align__(16) float sqv_a[4][2][16 * 34];
    __shared__ __align__(16) float avb_a[4][2][16 * 68];
    __shared__ __align__(16) float Bts_a[4][2][32];
    __shared__ __align__(16) f16   c16s_a[4][2][16 * 40];
    __shared__ __align__(16) float PCs_a[4][2][16];
    __shared__ __align__(16) float o_a[4][2][16][34];

    const int tid = threadIdx.x;
    const int wid = tid >> 6;
    const int lane = tid & 63;
    const int pp = wid >> 1;        // pipeline 0..3
    const int role = wid & 1;       // 0 = solver, 1 = state keeper
    const int ptid = (role << 6) | lane;  // 0..127 within pipeline
    const int L16 = lane & 15, quad = lane >> 4;
    const int vl = lane >> 2, li = lane & 3;
    const int t_av = lane >> 1, halfsel = lane & 1;

    const int bh = blockIdx.x;
    const int b = bh >> 3, h = bh & 7;
    const int v0 = (blockIdx.y * 4 + pp) * 16;
    const size_t rowbase = (size_t)(b * TLEN) * HIDN + h * HD;
    const size_t gmatbase = (size_t)bh * NCH;

    // ---- zero this pipeline's LDS (one-time) ----
    {
        uint32_t* z;
        z = (uint32_t*)&Sp16_a[pp][0];      for (int i = ptid; i < 16 * 136 / 2;   i += 128) z[i] = 0u;
        z = (uint32_t*)&G_a[pp][0][0];      for (int i = ptid; i < 2 * 1024 / 2;   i += 128) z[i] = 0u;
        z = (uint32_t*)&Q_a[pp][0][0];      for (int i = ptid; i < 2 * 1024 / 2;   i += 128) z[i] = 0u;
        z = (uint32_t*)&skv_a[pp][0][0];    for (int i = ptid; i < 2 * 16 * 34;    i += 128) z[i] = 0u;
        z = (uint32_t*)&sqv_a[pp][0][0];    for (int i = ptid; i < 2 * 16 * 34;    i += 128) z[i] = 0u;
        z = (uint32_t*)&avb_a[pp][0][0];    for (int i = ptid; i < 2 * 16 * 68;    i += 128) z[i] = 0u;
        z = (uint32_t*)&Bts_a[pp][0][0];    for (int i = ptid; i < 2 * 32;         i += 128) z[i] = 0u;
        z = (uint32_t*)&c16s_a[pp][0][0];   for (int i = ptid; i < 2 * 16 * 40 / 2; i += 128) z[i] = 0u;
        z = (uint32_t*)&PCs_a[pp][0][0];    for (int i = ptid; i < 2 * 16;         i += 128) z[i] = 0u;
        z = (uint32_t*)&o_a[pp][0][0][0];   for (int i = ptid; i < 2 * 16 * 34;    i += 128) z[i] = 0u;
    }
    __syncthreads();

    if (role == 1) {
        // =================== W1: state keeper / stager ===================
        f16x8 kfA[2][4], qfA[2][4], kfB[2][4], qfB[2][4];
        f32x4 sreg[8];   // fp32 master state in registers: S[v=L16][k=kt*16+quad*4+r]
#pragma unroll
        for (int i = 0; i < 8; ++i) sreg[i] = (f32x4){0.f, 0.f, 0.f, 0.f};

        // ---- prologue: stage slot-0 consumables ----
        {
            size_t gb0 = gmatbase * 1024;
            *(uint4*)(&G_a[pp][0][lane * 16])     = *(const uint4*)(G_g  + gb0 + lane * 16);
            *(uint4*)(&G_a[pp][0][lane * 16 + 8]) = *(const uint4*)(G_g  + gb0 + lane * 16 + 8);
            *(uint4*)(&Q_a[pp][0][lane * 16])     = *(const uint4*)(KQ_g + gb0 + lane * 16);
            *(uint4*)(&Q_a[pp][0][lane * 16 + 8]) = *(const uint4*)(KQ_g + gb0 + lane * 16 + 8);
            size_t ga = rowbase + (size_t)t_av * HIDN + v0 + halfsel * 8;
            float4 ar0 = *(const float4*)(a_buf + ga);
            float4 ar1 = *(const float4*)(a_buf + ga + 4);
            uint4  vr  = *(const uint4*)(v16 + ga);
            float betr = beta_buf[((size_t)(b * TLEN) + t_av) * NHEAD + h];
            const f16* vh = (const f16*)&vr;
            const float* aa0 = (const float*)&ar0;
            const float* aa1 = (const float*)&ar1;
#pragma unroll
            for (int e = 0; e < 4; ++e) {
                float2 wv; wv.x = aa0[e]; wv.y = betr * (float)vh[e];
                *(float2*)(&avb_a[pp][0][(halfsel * 8 + e) * 68 + 2 * t_av]) = wv;
                float2 wu; wu.x = aa1[e]; wu.y = betr * (float)vh[4 + e];
                *(float2*)(&avb_a[pp][0][(halfsel * 8 + 4 + e) * 68 + 2 * t_av]) = wu;
            }
            if (halfsel == 0) Bts_a[pp][0][t_av] = betr;
        }
        __syncthreads();   // B1

#define DO_UPDATE_MM(KF, QF)                                                        \
        if (ch >= 1 && ch <= NCH - 2) {                                             \
            f16x8 ca = *(const f16x8*)(&c16s_a[pp][np][L16 * 40 + quad * 8]);       \
            float pc = PCs_a[pp][np][L16];                                          \
            const f16* ktb = KT_g + ((size_t)gmatbase + ch - 1) * 4096 + (size_t)L16 * 32 + quad * 8; \
            f16x8 bu[8];                                                            \
            _Pragma("unroll")                                                       \
            for (int kt = 0; kt < 8; ++kt)                                          \
                bu[kt] = *(const f16x8*)(ktb + (size_t)kt * 512);                   \
            _Pragma("unroll")                                                       \
            for (int kt = 0; kt < 8; ++kt) {                                        \
                f32x4 d = __builtin_amdgcn_mfma_f32_16x16x32_f16(bu[kt], ca, (f32x4){0, 0, 0, 0}, 0, 0, 0); \
                f32x4 s = sreg[kt];                                                 \
                s.x = fmaf(pc, s.x, d[0]);                                          \
                s.y = fmaf(pc, s.y, d[1]);                                          \
                s.z = fmaf(pc, s.z, d[2]);                                          \
                s.w = fmaf(pc, s.w, d[3]);                                          \
                sreg[kt] = s;                                                       \
                union { f16 e[4]; uint2 u2; } ph;                                   \
                ph.e[0] = (f16)s.x; ph.e[1] = (f16)s.y;                             \
                ph.e[2] = (f16)s.z; ph.e[3] = (f16)s.w;                             \
                *(uint2*)(&Sp16_a[pp][L16 * 136 + kt * 16 + quad * 4]) = ph.u2;     \
            }                                                                       \
            f32x4 accK[2], accQ[2];                                                 \
            accK[0] = (f32x4){0, 0, 0, 0}; accK[1] = (f32x4){0, 0, 0, 0};           \
            accQ[0] = (f32x4){0, 0, 0, 0}; accQ[1] = (f32x4){0, 0, 0, 0};           \
            _Pragma("unroll")                                                       \
            for (int kk = 0; kk < 4; ++kk) {                                        \
                f16x8 sf = *(const f16x8*)(&Sp16_a[pp][L16 * 136 + kk * 32 + quad * 8]); \
                _Pragma("unroll")                                                   \
                for (int nt = 0; nt < 2; ++nt) {                                    \
                    accK[nt] = __builtin_amdgcn_mfma_f32_16x16x32_f16(sf, KF[nt][kk], accK[nt], 0, 0, 0); \
                    accQ[nt] = __builtin_amdgcn_mfma_f32_16x16x32_f16(sf, QF[nt][kk], accQ[nt], 0, 0, 0); \
                }                                                                   \
            }                                                                       \
            _Pragma("unroll")                                                       \
            for (int nt = 0; nt < 2; ++nt) {                                        \
                int t = nt * 16 + L16;                                              \
                _Pragma("unroll")                                                   \
                for (int r = 0; r < 4; ++r) {                                       \
                    skv_a[pp][np][(quad * 4 + r) * 34 + t] = accK[nt][r];           \
                    sqv_a[pp][np][(quad * 4 + r) * 34 + t] = accQ[nt][r];           \
                }                                                                   \
            }                                                                       \
        }

#define DO_PREFETCH(KF, QF)                                                         \
        if (ch <= NCH - 3) {                                                        \
            int tp = (ch + 2) * SCAN_C;                                             \
            _Pragma("unroll")                                                       \
            for (int nt = 0; nt < 2; ++nt)                                          \
                _Pragma("unroll")                                                   \
                for (int kk = 0; kk < 4; ++kk) {                                    \
                    size_t g = rowbase + (size_t)(tp + nt * 16 + L16) * HIDN + kk * 32 + quad * 8; \
                    KF[nt][kk] = *(const f16x8*)(k16 + g);                          \
                    QF[nt][kk] = *(const f16x8*)(q16 + g);                          \
                }                                                                   \
        }

        for (int ch = 0; ch < NCH; ++ch) {
            const int p = ch & 1;
            const int np = p ^ 1;
            const bool haveNext = (ch + 1 < NCH);

            // (0) DMA staging of next-slot G/Q + early avb loads
            float4 ar0, ar1; uint4 vr; float betr = 0.f;
            if (haveNext) {
                size_t gbn = (gmatbase + ch + 1) * 1024;
                const f16* gG = G_g  + gbn + lane * 8;
                const f16* gQ = KQ_g + gbn + lane * 8;
                gload_lds16(gG,       &G_a[pp][np][0]);
                gload_lds16(gG + 512, &G_a[pp][np][512]);
                gload_lds16(gQ,       &Q_a[pp][np][0]);
                gload_lds16(gQ + 512, &Q_a[pp][np][512]);
                int tn = (ch + 1) * SCAN_C;
                size_t ga = rowbase + (size_t)(tn + t_av) * HIDN + v0 + halfsel * 8;
                ar0 = *(const float4*)(a_buf + ga);
                ar1 = *(const float4*)(a_buf + ga + 4);
                vr  = *(const uint4*)(v16 + ga);
                betr = beta_buf[((size_t)(b * TLEN) + tn + t_av) * NHEAD + h];
            }

            // (1) register prefetch into the idle regset (issue EARLY)
            if ((ch & 1) == 0) { DO_PREFETCH(kfB, qfB) }
            else               { DO_PREFETCH(kfA, qfA) }

            // (2) flush o of chunk ch-1 (coalesced float4 stores)
            if (ch >= 1) {
                const int fp = (ch - 1) & 1;
                const int tprev = (ch - 1) * SCAN_C;
                const int tt = lane >> 1;
                const int hh = (lane & 1) * 8;
                float v8[8];
#pragma unroll
                for (int j = 0; j < 8; ++j) v8[j] = o_a[pp][fp][hh + j][tt];
                float4 f0; f0.x = v8[0]; f0.y = v8[1]; f0.z = v8[2]; f0.w = v8[3];
                float4 f1; f1.x = v8[4]; f1.y = v8[5]; f1.z = v8[6]; f1.w = v8[7];
                size_t ob = rowbase + (size_t)(tprev + tt) * HIDN + v0 + hh;
                *(float4*)(o_buf + ob)     = f0;
                *(float4*)(o_buf + ob + 4) = f1;
            }

            // (3) state update + stale-state MM with current regset
            if ((ch & 1) == 0) { DO_UPDATE_MM(kfA, qfA) }
            else               { DO_UPDATE_MM(kfB, qfB) }

            // (4) avb LDS writes (late)
            if (haveNext) {
                const f16* vh = (const f16*)&vr;
                const float* aa0 = (const float*)&ar0;
                const float* aa1 = (const float*)&ar1;
#pragma unroll
                for (int e = 0; e < 4; ++e) {
                    float2 wv; wv.x = aa0[e]; wv.y = betr * (float)vh[e];
                    *(float2*)(&avb_a[pp][np][(halfsel * 8 + e) * 68 + 2 * t_av]) = wv;
                    float2 wu; wu.x = aa1[e]; wu.y = betr * (float)vh[4 + e];
                    *(float2*)(&avb_a[pp][np][(halfsel * 8 + 4 + e) * 68 + 2 * t_av]) = wu;
                }
                if (halfsel == 0) Bts_a[pp][np][t_av] = betr;
            }
            __syncthreads();
        }
#undef DO_UPDATE_MM
#undef DO_PREFETCH

        // epilogue: flush o of the last chunk
        {
            const int fp = (NCH - 1) & 1;
            const int tprev = (NCH - 1) * SCAN_C;
            const int tt = lane >> 1;
            const int hh = (lane & 1) * 8;
            float v8[8];
#pragma unroll
            for (int j = 0; j < 8; ++j) v8[j] = o_a[pp][fp][hh + j][tt];
            float4 f0; f0.x = v8[0]; f0.y = v8[1]; f0.z = v8[2]; f0.w = v8[3];
            float4 f1; f1.x = v8[4]; f1.y = v8[5]; f1.z = v8[6]; f1.w = v8[7];
            size_t ob = rowbase + (size_t)(tprev + tt) * HIDN + v0 + hh;
            *(float4*)(o_buf + ob)     = f0;
            *(float4*)(o_buf + ob + 4) = f1;
        }
    } else {
        // =================== W0: serial critical path ===================
        f16x8 bxA[2], byA[2], bxB[2], byB[2];
        // prologue: prefetch Gx/Qx frags for ch=0 (c16s is zero then; value irrelevant, clamp idx)
#pragma unroll
        for (int nt = 0; nt < 2; ++nt) {
            size_t gx0 = (size_t)gmatbase * 1024 + (size_t)(nt * 16 + L16) * 32 + quad * 8;
            bxA[nt] = *(const f16x8*)(Gx_g + gx0);
            byA[nt] = *(const f16x8*)(Qx_g + gx0);
        }
        __builtin_amdgcn_s_setprio(1);
        __syncthreads();   // B1 pair

        for (int ch = 0; ch < NCH; ++ch) {
            const int p = ch & 1;
            const int np = p ^ 1;

            // ---- cross-chunk fixup: sk = P*sk_stale + c~_{ch-1} . Gx (in place) ----
            {
                f16x8 caf = *(const f16x8*)(&c16s_a[pp][np][L16 * 40 + quad * 8]);
                f32x4 fK[2], fQ[2];
#pragma unroll
                for (int nt = 0; nt < 2; ++nt) {
                    f16x8 bx = (p == 0) ? bxA[nt] : bxB[nt];
                    f16x8 by = (p == 0) ? byA[nt] : byB[nt];
                    fK[nt] = __builtin_amdgcn_mfma_f32_16x16x32_f16(caf, bx, (f32x4){0, 0, 0, 0}, 0, 0, 0);
                    fQ[nt] = __builtin_amdgcn_mfma_f32_16x16x32_f16(caf, by, (f32x4){0, 0, 0, 0}, 0, 0, 0);
                }
#pragma unroll
                for (int r = 0; r < 4; ++r) {
                    int vv = quad * 4 + r;
                    float Pv = PCs_a[pp][np][vv];
#pragma unroll
                    for (int nt = 0; nt < 2; ++nt) {
                        int t = nt * 16 + L16;
                        skv_a[pp][p][vv * 34 + t] = fmaf(Pv, skv_a[pp][p][vv * 34 + t], fK[nt][r]);
                        sqv_a[pp][p][vv * 34 + t] = fmaf(Pv, sqv_a[pp][p][vv * 34 + t], fQ[nt][r]);
                    }
                }
            }

            // prefetch next chunk's Gx/Qx frags into the other regset (boundary ch -> ch+1)
            if (ch + 1 < NCH) {
#pragma unroll
                for (int nt = 0; nt < 2; ++nt) {
                    size_t gxn = ((size_t)gmatbase + ch) * 1024 + (size_t)(nt * 16 + L16) * 32 + quad * 8;
                    if (p == 0) { bxB[nt] = *(const f16x8*)(Gx_g + gxn); byB[nt] = *(const f16x8*)(Qx_g + gxn); }
                    else        { bxA[nt] = *(const f16x8*)(Gx_g + gxn); byA[nt] = *(const f16x8*)(Qx_g + gxn); }
                }
            }

            // ---- triangular solve: 4 windows of {bulk LDS gather -> 4 reg-only iters} ----
            {
                f16x2 c0, c1, c2, c3;
                c0.x = (f16)0.f; c0.y = (f16)0.f; c1 = c0; c2 = c0; c3 = c0;
                float P = 1.f;
                union RowU { uint4 u4; f16x2 h2[4]; };

#pragma unroll
                for (int wnd = 0; wnd < 4; ++wnd) {
                    const int tw = wnd * 8;
                    uint4  bg0[4], bg1[4], bh0[4], bh1[4];
                    float2 bskp[4], bsqp[4], bbtp[4];
                    float4 bab4[4];
                    float  bkq00[4], bg01[4];
                    f16x2  bdq[4];
#pragma unroll
                    for (int i = 0; i < 4; ++i) {
                        const int t = tw + i * 2;
                        bg0[i] = *(const uint4*)(&G_a[pp][p][t * 32 + li * 8]);
                        bg1[i] = *(const uint4*)(&G_a[pp][p][(t + 1) * 32 + li * 8]);
                        bh0[i] = *(const uint4*)(&Q_a[pp][p][t * 32 + li * 8]);
                        bh1[i] = *(const uint4*)(&Q_a[pp][p][(t + 1) * 32 + li * 8]);
                        bskp[i] = *(const float2*)(&skv_a[pp][p][vl * 34 + t]);
                        bsqp[i] = *(const float2*)(&sqv_a[pp][p][vl * 34 + t]);
                        bab4[i] = *(const float4*)(&avb_a[pp][p][vl * 68 + 2 * t]);
                        bbtp[i] = *(const float2*)(&Bts_a[pp][p][t]);
                        bkq00[i] = (float)Q_a[pp][p][t * 32 + t];
                        bdq[i]  = *(const f16x2*)(&Q_a[pp][p][(t + 1) * 32 + t]);
                        bg01[i] = (float)G_a[pp][p][(t + 1) * 32 + t];
                    }
#pragma unroll
                    for (int i = 0; i < 4; ++i) {
                        const int t = tw + i * 2;
                        RowU g0u, g1u, h0u, h1u;
                        g0u.u4 = bg0[i]; g1u.u4 = bg1[i];
                        h0u.u4 = bh0[i]; h1u.u4 = bh1[i];
                        float2 skp = bskp[i], sqp = bsqp[i], btp = bbtp[i];
                        float4 ab4 = bab4[i];
                        float kq00 = bkq00[i], g01 = bg01[i];
                        f16x2 dq = bdq[i];

                        float pG  = fdot2_(c0, g0u.h2[0], fdot2_(c1, g0u.h2[1], 0.f))
                                  + fdot2_(c2, g0u.h2[2], fdot2_(c3, g0u.h2[3], 0.f));
                        float pG1 = fdot2_(c0, g1u.h2[0], fdot2_(c1, g1u.h2[1], 0.f))
                                  + fdot2_(c2, g1u.h2[2], fdot2_(c3, g1u.h2[3], 0.f));
                        float pO  = fdot2_(c0, h0u.h2[0], fdot2_(c1, h0u.h2[1], 0.f))
                                  + fdot2_(c2, h0u.h2[2], fdot2_(c3, h0u.h2[3], 0.f));
                        float pO1 = fdot2_(c0, h1u.h2[0], fdot2_(c1, h1u.h2[1], 0.f))
                                  + fdot2_(c2, h1u.h2[2], fdot2_(c3, h1u.h2[3], 0.f));
                        int tmp;
                        tmp = __builtin_amdgcn_update_dpp(0, __float_as_int(pG),  0xB1, 0xF, 0xF, true); pG  += __int_as_float(tmp);
                        tmp = __builtin_amdgcn_update_dpp(0, __float_as_int(pG1), 0xB1, 0xF, 0xF, true); pG1 += __int_as_float(tmp);
                        tmp = __builtin_amdgcn_update_dpp(0, __float_as_int(pO),  0xB1, 0xF, 0xF, true); pO  += __int_as_float(tmp);
                        tmp = __builtin_amdgcn_update_dpp(0, __float_as_int(pO1), 0xB1, 0xF, 0xF, true); pO1 += __int_as_float(tmp);
                        tmp = __builtin_amdgcn_update_dpp(0, __float_as_int(pG),  0x4E, 0xF, 0xF, true); pG  += __int_as_float(tmp);
                        tmp = __builtin_amdgcn_update_dpp(0, __float_as_int(pG1), 0x4E, 0xF, 0xF, true); pG1 += __int_as_float(tmp);
                        tmp = __builtin_amdgcn_update_dpp(0, __float_as_int(pO),  0x4E, 0xF, 0xF, true); pO  += __int_as_float(tmp);
                        tmp = __builtin_amdgcn_update_dpp(0, __float_as_int(pO1), 0x4E, 0xF, 0xF, true); pO1 += __int_as_float(tmp);

                        float a0 = ab4.x, bv0 = ab4.y, a1 = ab4.z, bv1 = ab4.w;
                        float bt0 = btp.x, bt1 = btp.y;
                        float sk0 = skp.x * ISSC, sk1 = skp.y * ISSC;
                        float sq0 = sqp.x * ISSC, sq1 = sqp.y * ISSC;
                        float kq01 = (float)dq.x, kq11 = (float)dq.y;

                        // step t
                        float x0 = fmaf(P, sk0, pG);
                        float u0 = fmaf(-bt0, x0, bv0);
                        float P0 = P * a0;
                        float o0 = fmaf(a0, pO, u0 * kq00);
                        o0 = fmaf(P0, sq0, o0);
                        // step t+1 (cross-terms via u0 explicitly)
                        float accGv = fmaf(a0, pG1, u0 * g01);
                        float x1 = fmaf(P0, sk1, accGv);
                        float u1 = fmaf(-bt1, x1, bv1);
                        float P1 = P0 * a1;
                        float accOv = fmaf(a0, pO1, u0 * kq01);
                        float o1 = fmaf(a1, accOv, u1 * kq11);
                        o1 = fmaf(P1, sq1, o1);

                        float aa = a0 * a1;
                        f16 aah = (f16)aa;
                        f16x2 aa2; aa2.x = aah; aa2.y = aah;
                        c0 *= aa2; c1 *= aa2; c2 *= aa2; c3 *= aa2;
                        if (li == (t >> 3)) {
                            f16x2 un; un.x = (f16)(u0 * a1); un.y = (f16)u1;
                            int sel = (t & 7) >> 1;
                            if (sel == 0) c0 = un; else if (sel == 1) c1 = un;
                            else if (sel == 2) c2 = un; else c3 = un;
                        }
                        P = P1;
                        if (li == 0) {
                            float2 o2; o2.x = o0; o2.y = o1;
                            *(float2*)(&o_a[pp][p][vl][t]) = o2;
                        }
                    }
                }
                f16 s16 = (f16)SSC;
                f16x2 ss2; ss2.x = s16; ss2.y = s16;
                union { f16x2 h2[4]; uint4 u4; } pc;
                pc.h2[0] = c0 * ss2; pc.h2[1] = c1 * ss2; pc.h2[2] = c2 * ss2; pc.h2[3] = c3 * ss2;
                *(uint4*)(&c16s_a[pp][p][vl * 40 + li * 8]) = pc.u4;
                if (li == 0) PCs_a[pp][p][vl] = P;
            }
            __syncthreads();
        }
    }
}

// ---------------------------------------------------------------------------
// K6: LayerNorm over head dim, * g, -> f16 for output GEMM
__global__ __launch_bounds__(256) void ln_gate_kernel(
    const float* __restrict__ o_buf, const f16* __restrict__ g16,
    const float* __restrict__ lng, const float* __restrict__ lnb,
    f16* __restrict__ og16)
{
    int row = blockIdx.x;
    int h = threadIdx.x >> 5, lane = threadIdx.x & 31;
    size_t base = (size_t)row * HIDN + h * HD + lane * 4;
    float4 x = *(const float4*)(o_buf + base);
    float s  = x.x + x.y + x.z + x.w;
    float sq = x.x * x.x + x.y * x.y + x.z * x.z + x.w * x.w;
#pragma unroll
    for (int m = 1; m <= 16; m <<= 1) {
        s  += __shfl_xor(s, m);
        sq += __shfl_xor(sq, m);
    }
    float mu  = s * (1.0f / 128.0f);
    float var = sq * (1.0f / 128.0f) - mu * mu;
    float inv = 1.0f / sqrtf(var + 1e-5f);
    int d = lane * 4;
    const float* xp = (const float*)&x;
    union { f16 h4[4]; uint2 u; } pk;
#pragma unroll
    for (int j = 0; j < 4; ++j) {
        float on = (xp[j] - mu) * inv * lng[d + j] + lnb[d + j];
        pk.h4[j] = (f16)(on * (float)g16[base + j]);
    }
    *(uint2*)(og16 + base) = pk.u;
}

// ---------------------------------------------------------------------------
extern "C" void kernel_launch(void* const* d_in, const int* in_sizes, int n_in,
                              void* d_out, int out_size, void* d_ws, size_t ws_size,
                              hipStream_t stream)
{
    (void)in_sizes; (void)n_in; (void)out_size; (void)ws_size;
    const float* x   = (const float*)d_in[0];
    const float* Wq  = (const float*)d_in[1];
    const float* Wk  = (const float*)d_in[2];
    const float* Wv  = (const float*)d_in[3];
    const float* Wa  = (const float*)d_in[4];
    const float* ba  = (const float*)d_in[5];
    const float* Wb  = (const float*)d_in[6];
    const float* bb  = (const float*)d_in[7];
    const float* Wg  = (const float*)d_in[8];
    const float* Wo  = (const float*)d_in[9];
    const float* cqw = (const float*)d_in[10];
    const float* cqb = (const float*)d_in[11];
    const float* ckw = (const float*)d_in[12];
    const float* ckb = (const float*)d_in[13];
    const float* cvw = (const float*)d_in[14];
    const float* cvb = (const float*)d_in[15];
    const float* lng = (const float*)d_in[16];
    const float* lnb = (const float*)d_in[17];
    float* out = (float*)d_out;

    char* ws = (char*)d_ws;
    f16*   x16      = (f16*)(ws + 0);                 //  8,388,608 B
    f16*   WT       = (f16*)(ws + 8388608);           // 12,582,912 B
    f16*   qkvh     = (f16*)(ws + 20971520);          // 25,165,824 B (reused by gram outputs)
    f16*   qkv16    = (f16*)(ws + 46137344);          // 25,165,824 B (f16 q,k,v post-conv)
    float* a_buf    = (float*)(ws + 96468992);        // 16,777,216 B
    f16*   g16      = (f16*)(ws + 113246208);         //  8,388,608 B
    float* beta_buf = (float*)(ws + 121634816);       //    131,072 B
    float* o_buf    = (float*)(ws + 121765888);       // 16,777,216 B
    f16*   og16     = (f16*)(ws + 138543104);         //  8,388,608 B

    // gram pre-pass outputs reuse the (dead after conv) qkvh region: 16 MB <= 24 MB
    f16* G_g  = qkvh;                 // 16*64*1024 f16 = 2 MB
    f16* KQ_g = qkvh + 1048576;       // 2 MB
    f16* Gx_g = qkvh + 2097152;       // 2 MB
    f16* Qx_g = qkvh + 3145728;       // 2 MB
    f16* KT_g = qkvh + 4194304;       // 16*64*4096 f16 = 8 MB

    convert_x_kernel<<<dim3(4096), dim3(256), 0, stream>>>(x, x16);
    transpose_convert_kernel<<<dim3(32, 32, 6), dim3(256), 0, stream>>>(Wq, Wk, Wv, Wa, Wg, Wo, WT);
    gemm_f16<0><<<dim3(40, 32), dim3(256), 0, stream>>>(x16, WT, nullptr, qkvh, a_buf, g16, ba);
    beta_kernel<<<dim3(4096), dim3(256), 0, stream>>>(x, Wb, bb, beta_buf);
    conv_silu_kernel<<<dim3(4096, 3), dim3(256), 0, stream>>>(qkvh, cqw, cqb, ckw, ckb, cvw, cvb, qkv16);
    gram_kernel<<<dim3(NCH, 16), dim3(64), 0, stream>>>(
        qkv16, qkv16 + XELEMS, G_g, KQ_g, Gx_g, Qx_g, KT_g);
    scan2_kernel<<<dim3(16, 2), dim3(512), 0, stream>>>(
        qkv16, qkv16 + XELEMS, qkv16 + 2 * (size_t)XELEMS, a_buf, beta_buf,
        G_g, KQ_g, Gx_g, Qx_g, KT_g, o_buf);
    ln_gate_kernel<<<dim3(4096), dim3(256), 0, stream>>>(o_buf, g16, lng, lnb, og16);
    gemm_f16<1><<<dim3(8, 32), dim3(256), 0, stream>>>(og16, WT + 5 * (size_t)MAT_ELEMS, out,
                                                       nullptr, nullptr, nullptr, nullptr);
}

// Round 8
// 512.488 us; speedup vs baseline: 1.4023x; 1.4023x over previous
//
#include <hip/hip_runtime.h>
#include <hip/hip_bf16.h>
#include <cstdint>
#include <cstddef>

// Problem dims (fixed)
#define BATCH 2
#define TLEN  2048
#define NHEAD 8
#define HD    128
#define HIDN  1024
#define MTOT  4096          // BATCH*TLEN
#define MAT_ELEMS 1048576   // 1024*1024
#define XELEMS 4194304      // 4096*1024
#define SCAN_C 32
#define NCH    64           // TLEN / SCAN_C
#define SSC  1024.0f
#define ISSC 0.0009765625f

typedef _Float16 f16;
typedef _Float16 f16x2 __attribute__((ext_vector_type(2)));
typedef _Float16 f16x8 __attribute__((ext_vector_type(8)));
typedef float    f32x4 __attribute__((ext_vector_type(4)));

__device__ __forceinline__ float sigmoidf_(float v) { return 1.0f / (1.0f + __expf(-v)); }

// f16x2 dot with f32 accumulate: v_dot2_f32_f16 (exact products, f32 accum)
__device__ __forceinline__ float fdot2_(f16x2 a, f16x2 b, float c)
{
#if __has_builtin(__builtin_amdgcn_fdot2)
    return __builtin_amdgcn_fdot2(a, b, c, false);
#else
    return fmaf((float)a.x, (float)b.x, fmaf((float)a.y, (float)b.y, c));
#endif
}

// async global->LDS DMA: 16B per lane, LDS dest = wave-uniform base + lane*16B
__device__ __forceinline__ void gload_lds16(const f16* g, f16* l)
{
    __builtin_amdgcn_global_load_lds(
        (const __attribute__((address_space(1))) uint32_t*)(g),
        (__attribute__((address_space(3))) uint32_t*)(l), 16, 0, 0);
}

// ---------------------------------------------------------------------------
// K0: convert x (fp32) -> f16
__global__ __launch_bounds__(256) void convert_x_kernel(const float* __restrict__ x,
                                                        f16* __restrict__ x16)
{
    int i = (blockIdx.x * 256 + threadIdx.x) * 4;
    float4 v = *(const float4*)(x + i);
    union { f16 h[4]; uint2 u; } pk;
    pk.h[0] = (f16)v.x; pk.h[1] = (f16)v.y; pk.h[2] = (f16)v.z; pk.h[3] = (f16)v.w;
    *(uint2*)(x16 + i) = pk.u;
}

// ---------------------------------------------------------------------------
// K1: transpose-convert the six 1024x1024 weight matrices to f16 WT[mat][n][k]
__global__ __launch_bounds__(256) void transpose_convert_kernel(
    const float* __restrict__ Wq, const float* __restrict__ Wk, const float* __restrict__ Wv,
    const float* __restrict__ Wa, const float* __restrict__ Wg, const float* __restrict__ Wo,
    f16* __restrict__ WT)
{
    __shared__ float tile[32][33];
    int mat = blockIdx.z;
    const float* W = (mat == 0) ? Wq : (mat == 1) ? Wk : (mat == 2) ? Wv
                   : (mat == 3) ? Wa : (mat == 4) ? Wg : Wo;
    int k0 = blockIdx.y * 32, n0 = blockIdx.x * 32;
    int tr = threadIdx.x >> 3;
    int tc = (threadIdx.x & 7) * 4;
    float4 vin = *(const float4*)(W + (size_t)(k0 + tr) * HIDN + n0 + tc);
    tile[tr][tc + 0] = vin.x; tile[tr][tc + 1] = vin.y;
    tile[tr][tc + 2] = vin.z; tile[tr][tc + 3] = vin.w;
    __syncthreads();
    f16* dst = WT + (size_t)(mat * HIDN + n0 + tr) * HIDN + k0 + tc;
    union { f16 h[4]; uint2 u; } pk;
    pk.h[0] = (f16)tile[tc + 0][tr]; pk.h[1] = (f16)tile[tc + 1][tr];
    pk.h[2] = (f16)tile[tc + 2][tr]; pk.h[3] = (f16)tile[tc + 3][tr];
    *(uint2*)dst = pk.u;
}

// ---------------------------------------------------------------------------
// K2/K7: f16 MFMA GEMM, C = A[M,1024] @ BT[n][k]^T, 128x128 tile, BK=32.
// m97 structure: global_load_lds width=16 staging into linear [128][32] tiles.
// XCD-aware bijective workgroup swizzle (T1): neighbor tiles share A/B panels
// -> keep them on the same XCD's L2.
template <int MODE>
__global__ __launch_bounds__(256) void gemm_f16(
    const f16* __restrict__ A, const f16* __restrict__ BT,
    float* __restrict__ out_f32,
    f16* __restrict__ qkv_hat, float* __restrict__ a_buf, f16* __restrict__ g16,
    const float* __restrict__ ba)
{
    __shared__ __align__(16) f16 As[128][32];
    __shared__ __align__(16) f16 Bs[128][32];

    // XCD swizzle (bijective since nwg % 8 == 0 for both launches)
    int nwg = gridDim.x * gridDim.y;
    int wg  = blockIdx.y * gridDim.x + blockIdx.x;
    int qq  = nwg >> 3;
    int swz = (wg & 7) * qq + (wg >> 3);
    int bx  = swz % gridDim.x;
    int by  = swz / gridDim.x;

    int m0 = by * 128;
    int n0 = bx * 128;
    int tid = threadIdx.x;
    int w = tid >> 6, lane = tid & 63;
    int L16 = lane & 15, quad = lane >> 4;
    int wm = (w >> 1) * 64, wn = (w & 1) * 64;

    f32x4 acc[4][4];
#pragma unroll
    for (int i = 0; i < 4; ++i)
#pragma unroll
        for (int j = 0; j < 4; ++j) acc[i][j] = (f32x4){0.f, 0.f, 0.f, 0.f};

    int ldr = tid >> 2;            // 0..63
    int ldc = (tid & 3) * 8;
    f16* asb0 = &As[0][0]  + w * 512;
    f16* asb1 = &As[64][0] + w * 512;
    f16* bsb0 = &Bs[0][0]  + w * 512;
    f16* bsb1 = &Bs[64][0] + w * 512;

    for (int k0 = 0; k0 < 1024; k0 += 32) {
        __syncthreads();
        gload_lds16(A  + (size_t)(m0 + ldr) * HIDN + k0 + ldc,      asb0);
        gload_lds16(A  + (size_t)(m0 + ldr + 64) * HIDN + k0 + ldc, asb1);
        gload_lds16(BT + (size_t)(n0 + ldr) * HIDN + k0 + ldc,      bsb0);
        gload_lds16(BT + (size_t)(n0 + ldr + 64) * HIDN + k0 + ldc, bsb1);
        __syncthreads();
        f16x8 af[4], bf[4];
#pragma unroll
        for (int i = 0; i < 4; ++i) {
            af[i] = *(const f16x8*)(&As[wm + i * 16 + L16][quad * 8]);
            bf[i] = *(const f16x8*)(&Bs[wn + i * 16 + L16][quad * 8]);
        }
#pragma unroll
        for (int i = 0; i < 4; ++i)
#pragma unroll
            for (int j = 0; j < 4; ++j)
                acc[i][j] = __builtin_amdgcn_mfma_f32_16x16x32_f16(af[i], bf[j], acc[i][j], 0, 0, 0);
    }

#pragma unroll
    for (int i = 0; i < 4; ++i) {
#pragma unroll
        for (int j = 0; j < 4; ++j) {
            f32x4 c = acc[i][j];
            int mbase = m0 + wm + i * 16 + quad * 4;
            int n = n0 + wn + j * 16 + L16;
            if (MODE == 1) {
#pragma unroll
                for (int r = 0; r < 4; ++r)
                    out_f32[(size_t)(mbase + r) * HIDN + n] = c[r];
            } else {
                int mat = n >> 10;
                int nn = n & 1023;
                if (mat < 3) {
#pragma unroll
                    for (int r = 0; r < 4; ++r)
                        qkv_hat[(size_t)mat * XELEMS + (size_t)(mbase + r) * HIDN + nn] = (f16)c[r];
                } else if (mat == 3) {
                    float bav = ba[nn];
#pragma unroll
                    for (int r = 0; r < 4; ++r)
                        a_buf[(size_t)(mbase + r) * HIDN + nn] = sigmoidf_(c[r] + bav);
                } else {
#pragma unroll
                    for (int r = 0; r < 4; ++r)
                        g16[(size_t)(mbase + r) * HIDN + nn] = (f16)sigmoidf_(c[r]);
                }
            }
        }
    }
}

// ---------------------------------------------------------------------------
// K3: beta = sigmoid(x @ Wb + bb), fp32 exact path.
__global__ __launch_bounds__(256) void beta_kernel(const float* __restrict__ x,
                                                   const float* __restrict__ Wb,
                                                   const float* __restrict__ bb,
                                                   float* __restrict__ beta_buf)
{
    int row = blockIdx.x;
    int h = threadIdx.x >> 5, lane = threadIdx.x & 31;
    const float* xr = x + (size_t)row * HIDN;
    float part = 0.f;
    for (int i = lane; i < HIDN; i += 32)
        part += xr[i] * Wb[i * NHEAD + h];
#pragma unroll
    for (int m = 1; m <= 16; m <<= 1) part += __shfl_xor(part, m);
    if (lane == 0)
        beta_buf[(size_t)row * NHEAD + h] = sigmoidf_(part + bb[h]);
}

// ---------------------------------------------------------------------------
// K4: causal depthwise conv (K=4) + SiLU (+ scale for k), f16 output.
__global__ __launch_bounds__(256) void conv_silu_kernel(
    const f16* __restrict__ qkv_hat,
    const float* __restrict__ cqw, const float* __restrict__ cqb,
    const float* __restrict__ ckw, const float* __restrict__ ckb,
    const float* __restrict__ cvw, const float* __restrict__ cvb,
    f16* __restrict__ qkv16)
{
    int z = blockIdx.y;
    int row = blockIdx.x;
    int tloc = row & (TLEN - 1);
    int c4 = threadIdx.x * 4;
    const f16* src = qkv_hat + (size_t)z * XELEMS;
    const float* w  = (z == 0) ? cqw : (z == 1) ? ckw : cvw;
    const float* bi = (z == 0) ? cqb : (z == 1) ? ckb : cvb;

    float xv[4][4];
#pragma unroll
    for (int j = 0; j < 4; ++j) {
        int tt = tloc - 3 + j;
        if (tt >= 0) {
            const f16* p = src + (size_t)(row - 3 + j) * HIDN + c4;
            xv[j][0] = (float)p[0]; xv[j][1] = (float)p[1];
            xv[j][2] = (float)p[2]; xv[j][3] = (float)p[3];
        } else {
            xv[j][0] = xv[j][1] = xv[j][2] = xv[j][3] = 0.f;
        }
    }
    float scale = (z == 1) ? 0.08838834764831845f : 1.0f;  // 128^-0.5 for k
    union { f16 h[4]; uint2 u; } pk;
#pragma unroll
    for (int cc = 0; cc < 4; ++cc) {
        float4 wc = *(const float4*)(w + (size_t)(c4 + cc) * 4);
        float acc = bi[c4 + cc] + wc.x * xv[0][cc] + wc.y * xv[1][cc]
                                 + wc.z * xv[2][cc] + wc.w * xv[3][cc];
        pk.h[cc] = (f16)(acc * sigmoidf_(acc) * scale);
    }
    *(uint2*)(qkv16 + (size_t)z * XELEMS + (size_t)row * HIDN + c4) = pk.u;
}

// ---------------------------------------------------------------------------
// K4b: gram pre-pass. Per (chunk, bh): all state-INDEPENDENT chunk matrices.
__global__ __launch_bounds__(64) void gram_kernel(
    const f16* __restrict__ q16, const f16* __restrict__ k16,
    f16* __restrict__ G_g, f16* __restrict__ KQ_g,
    f16* __restrict__ Gx_g, f16* __restrict__ Qx_g, f16* __restrict__ KT_g)
{
    int ch = blockIdx.x;
    int bh = blockIdx.y;
    int b = bh >> 3, h = bh & 7;
    int lane = threadIdx.x;
    int L16 = lane & 15, quad = lane >> 4;
    size_t rowbase = (size_t)(b * TLEN) * HIDN + h * HD;
    int t0 = ch * SCAN_C;
    bool hasNext = (ch + 1 < NCH);

    union ZU { uint4 u; f16x8 v; };
    ZU zz; zz.u = (uint4){0, 0, 0, 0};

    f16x8 kc[2][4], qc[2][4], kn[2][4], qn[2][4];
#pragma unroll
    for (int nt = 0; nt < 2; ++nt)
#pragma unroll
        for (int kk = 0; kk < 4; ++kk) {
            size_t g = rowbase + (size_t)(t0 + nt * 16 + L16) * HIDN + kk * 32 + quad * 8;
            kc[nt][kk] = *(const f16x8*)(k16 + g);
            qc[nt][kk] = *(const f16x8*)(q16 + g);
            if (hasNext) {
                kn[nt][kk] = *(const f16x8*)(k16 + g + (size_t)SCAN_C * HIDN);
                qn[nt][kk] = *(const f16x8*)(q16 + g + (size_t)SCAN_C * HIDN);
            } else {
                kn[nt][kk] = zz.v; qn[nt][kk] = zz.v;
            }
        }

    f32x4 aG[2][2], aKQ[2][2], aGx[2][2], aQx[2][2];
#pragma unroll
    for (int i = 0; i < 2; ++i)
#pragma unroll
        for (int j = 0; j < 2; ++j) {
            aG[i][j] = (f32x4){0, 0, 0, 0}; aKQ[i][j] = (f32x4){0, 0, 0, 0};
            aGx[i][j] = (f32x4){0, 0, 0, 0}; aQx[i][j] = (f32x4){0, 0, 0, 0};
        }
#pragma unroll
    for (int kk = 0; kk < 4; ++kk)
#pragma unroll
        for (int mt = 0; mt < 2; ++mt)
#pragma unroll
            for (int nt = 0; nt < 2; ++nt) {
                aG[mt][nt]  = __builtin_amdgcn_mfma_f32_16x16x32_f16(kc[mt][kk], kc[nt][kk], aG[mt][nt], 0, 0, 0);
                aKQ[mt][nt] = __builtin_amdgcn_mfma_f32_16x16x32_f16(kc[mt][kk], qc[nt][kk], aKQ[mt][nt], 0, 0, 0);
                aGx[mt][nt] = __builtin_amdgcn_mfma_f32_16x16x32_f16(kc[mt][kk], kn[nt][kk], aGx[mt][nt], 0, 0, 0);
                aQx[mt][nt] = __builtin_amdgcn_mfma_f32_16x16x32_f16(kc[mt][kk], qn[nt][kk], aQx[mt][nt], 0, 0, 0);
            }

    size_t gb = ((size_t)bh * NCH + ch) * 1024;
#pragma unroll
    for (int nt = 0; nt < 2; ++nt) {
        int t = nt * 16 + L16;
#pragma unroll
        for (int mt = 0; mt < 2; ++mt) {
            union { f16 e[4]; uint2 u2; } pg, pq, px, py;
#pragma unroll
            for (int r = 0; r < 4; ++r) {
                pg.e[r] = (f16)aG[mt][nt][r];
                pq.e[r] = (f16)aKQ[mt][nt][r];
                px.e[r] = (f16)aGx[mt][nt][r];
                py.e[r] = (f16)aQx[mt][nt][r];
            }
            *(uint2*)(G_g  + gb + t * 32 + mt * 16 + quad * 4) = pg.u2;
            *(uint2*)(KQ_g + gb + t * 32 + mt * 16 + quad * 4) = pq.u2;
            *(uint2*)(Gx_g + gb + t * 32 + mt * 16 + quad * 4) = px.u2;
            *(uint2*)(Qx_g + gb + t * 32 + mt * 16 + quad * 4) = py.u2;
        }
    }
    // K^T store (scalar f16, off critical path of the serial scan)
    size_t kb = ((size_t)bh * NCH + ch) * 4096;
#pragma unroll
    for (int nt = 0; nt < 2; ++nt) {
        int t = nt * 16 + L16;
#pragma unroll
        for (int kk = 0; kk < 4; ++kk)
#pragma unroll
            for (int j = 0; j < 8; ++j) {
                int k = kk * 32 + quad * 8 + j;
                KT_g[kb + (size_t)k * 32 + t] = kc[nt][kk][j];
            }
    }
}

// ---------------------------------------------------------------------------
// K5: producer/consumer chunked delta-rule scan (R6 structure — best verified).
//  wave0 = serial critical path: cross-chunk fixup (4 MFMA) + triangular solve
//          as 4 windows/chunk: bulk-gather ALL LDS inputs for 4 iterations
//          back-to-back, then 4 iterations of register-resident compute.
//  wave1 = state update + stale-state MM + DMA staging + prefetch + o-flush.
__global__ __launch_bounds__(128, 1) void scan2_kernel(
    const f16* __restrict__ q16, const f16* __restrict__ k16, const f16* __restrict__ v16,
    const float* __restrict__ a_buf, const float* __restrict__ beta_buf,
    const f16* __restrict__ G_g, const f16* __restrict__ KQ_g,
    const f16* __restrict__ Gx_g, const f16* __restrict__ Qx_g, const f16* __restrict__ KT_g,
    float* __restrict__ o_buf)
{
    __shared__ __align__(16) float Sp[16 * 132];      // fp32 master state, wave1-owned
    __shared__ __align__(16) f16   Sp16[16 * 136];    // f16 shadow, wave1-owned
    __shared__ __align__(16) f16   KT_lds2[2][4096];  // K^T double buffer (DMA dest)
    __shared__ __align__(16) f16   G_lds[2][1024];    // G[t*32+tau]
    __shared__ __align__(16) f16   Q_lds[2][1024];    // KQ[t*32+tau]
    __shared__ __align__(16) f16   Gx_lds[2][1024];   // cross gram
    __shared__ __align__(16) f16   Qx_lds[2][1024];
    __shared__ __align__(16) float skv[2][16 * 34];   // [v][t]; w1 writes stale, w0 fixes
    __shared__ __align__(16) float sqv[2][16 * 34];
    __shared__ __align__(16) float avb[2][16 * 68];   // [v][2t + {a, beta*v}]
    __shared__ __align__(16) float Bts[2][32];
    __shared__ __align__(16) f16   c16s[2][16 * 40];  // c~ (SSC-scaled)
    __shared__ __align__(16) float PCs[2][16];        // per-v chunk decay product
    __shared__ __align__(16) float o_lds[2][16][34];  // o staging [v][t], w0 -> w1 flush

    const int tid = threadIdx.x;
    const int wid = tid >> 6;
    const int lane = tid & 63;
    const int L16 = lane & 15, quad = lane >> 4;
    const int vl = lane >> 2, li = lane & 3;
    const int t_av = lane >> 1, halfsel = lane & 1;

    const int bh = blockIdx.x;
    const int b = bh >> 3, h = bh & 7;
    const int v0 = blockIdx.y * 16;
    const size_t rowbase = (size_t)(b * TLEN) * HIDN + h * HD;
    const size_t gmatbase = (size_t)bh * NCH;

    // ---- zero all LDS (one-time) ----
    {
        for (int i = tid; i < 16 * 132; i += 128) Sp[i] = 0.f;
        uint32_t* z;
        z = (uint32_t*)Sp16;    for (int i = tid; i < 16 * 136 / 2; i += 128) z[i] = 0u;
        z = (uint32_t*)KT_lds2; for (int i = tid; i < 2 * 4096 / 2; i += 128) z[i] = 0u;
        z = (uint32_t*)G_lds;   for (int i = tid; i < 1024;          i += 128) z[i] = 0u;
        z = (uint32_t*)Q_lds;   for (int i = tid; i < 1024;          i += 128) z[i] = 0u;
        z = (uint32_t*)Gx_lds;  for (int i = tid; i < 1024;          i += 128) z[i] = 0u;
        z = (uint32_t*)Qx_lds;  for (int i = tid; i < 1024;          i += 128) z[i] = 0u;
        z = (uint32_t*)skv;     for (int i = tid; i < 2 * 16 * 34;   i += 128) z[i] = 0u;
        z = (uint32_t*)sqv;     for (int i = tid; i < 2 * 16 * 34;   i += 128) z[i] = 0u;
        z = (uint32_t*)avb;     for (int i = tid; i < 2 * 16 * 68;   i += 128) z[i] = 0u;
        z = (uint32_t*)Bts;     for (int i = tid; i < 2 * 32;        i += 128) z[i] = 0u;
        z = (uint32_t*)c16s;    for (int i = tid; i < 2 * 16 * 40 / 2; i += 128) z[i] = 0u;
        z = (uint32_t*)PCs;     for (int i = tid; i < 2 * 16;        i += 128) z[i] = 0u;
    }
    __syncthreads();

    if (wid == 1) {
        // =================== WAVE 1: state keeper / stager ===================
        f16x8 kfA[2][4], qfA[2][4], kfB[2][4], qfB[2][4];

        // ---- prologue: stage slot-0 consumables (reg path, one-time) ----
        {
            size_t gb0 = gmatbase * 1024;
            *(uint4*)(&G_lds[0][lane * 16])     = *(const uint4*)(G_g  + gb0 + lane * 16);
            *(uint4*)(&G_lds[0][lane * 16 + 8]) = *(const uint4*)(G_g  + gb0 + lane * 16 + 8);
            *(uint4*)(&Q_lds[0][lane * 16])     = *(const uint4*)(KQ_g + gb0 + lane * 16);
            *(uint4*)(&Q_lds[0][lane * 16 + 8]) = *(const uint4*)(KQ_g + gb0 + lane * 16 + 8);
            size_t ga = rowbase + (size_t)t_av * HIDN + v0 + halfsel * 8;
            float4 ar0 = *(const float4*)(a_buf + ga);
            float4 ar1 = *(const float4*)(a_buf + ga + 4);
            uint4  vr  = *(const uint4*)(v16 + ga);
            float betr = beta_buf[((size_t)(b * TLEN) + t_av) * NHEAD + h];
            const f16* vh = (const f16*)&vr;
            const float* aa0 = (const float*)&ar0;
            const float* aa1 = (const float*)&ar1;
#pragma unroll
            for (int e = 0; e < 4; ++e) {
                float2 wv; wv.x = aa0[e]; wv.y = betr * (float)vh[e];
                *(float2*)(&avb[0][(halfsel * 8 + e) * 68 + 2 * t_av]) = wv;
                float2 wu; wu.x = aa1[e]; wu.y = betr * (float)vh[4 + e];
                *(float2*)(&avb[0][(halfsel * 8 + 4 + e) * 68 + 2 * t_av]) = wu;
            }
            if (halfsel == 0) Bts[0][t_av] = betr;
        }
        __syncthreads();   // B1

#define DO_UPDATE_MM(KF, QF)                                                        \
        if (ch >= 1 && ch <= NCH - 2) {                                             \
            f16x8 ca = *(const f16x8*)(&c16s[np][L16 * 40 + quad * 8]);             \
            float pc = PCs[np][L16];                                                \
            _Pragma("unroll")                                                       \
            for (int kt = 0; kt < 8; ++kt) {                                        \
                f16x8 bu = *(const f16x8*)(&KT_lds2[p][(kt * 16 + L16) * 32 + quad * 8]); \
                f32x4 d = __builtin_amdgcn_mfma_f32_16x16x32_f16(bu, ca, (f32x4){0, 0, 0, 0}, 0, 0, 0); \
                int idx = L16 * 132 + kt * 16 + quad * 4;                           \
                float4 s = *(const float4*)(&Sp[idx]);                              \
                s.x = fmaf(pc, s.x, d[0]);                                          \
                s.y = fmaf(pc, s.y, d[1]);                                          \
                s.z = fmaf(pc, s.z, d[2]);                                          \
                s.w = fmaf(pc, s.w, d[3]);                                          \
                *(float4*)(&Sp[idx]) = s;                                           \
                union { f16 e[4]; uint2 u2; } ph;                                   \
                ph.e[0] = (f16)s.x; ph.e[1] = (f16)s.y;                             \
                ph.e[2] = (f16)s.z; ph.e[3] = (f16)s.w;                             \
                *(uint2*)(&Sp16[L16 * 136 + kt * 16 + quad * 4]) = ph.u2;           \
            }                                                                       \
            f32x4 accK[2], accQ[2];                                                 \
            accK[0] = (f32x4){0, 0, 0, 0}; accK[1] = (f32x4){0, 0, 0, 0};           \
            accQ[0] = (f32x4){0, 0, 0, 0}; accQ[1] = (f32x4){0, 0, 0, 0};           \
            _Pragma("unroll")                                                       \
            for (int kk = 0; kk < 4; ++kk) {                                        \
                f16x8 sf = *(const f16x8*)(&Sp16[L16 * 136 + kk * 32 + quad * 8]);  \
                _Pragma("unroll")                                                   \
                for (int nt = 0; nt < 2; ++nt) {                                    \
                    accK[nt] = __builtin_amdgcn_mfma_f32_16x16x32_f16(sf, KF[nt][kk], accK[nt], 0, 0, 0); \
                    accQ[nt] = __builtin_amdgcn_mfma_f32_16x16x32_f16(sf, QF[nt][kk], accQ[nt], 0, 0, 0); \
                }                                                                   \
            }                                                                       \
            _Pragma("unroll")                                                       \
            for (int nt = 0; nt < 2; ++nt) {                                        \
                int t = nt * 16 + L16;                                              \
                _Pragma("unroll")                                                   \
                for (int r = 0; r < 4; ++r) {                                       \
                    skv[np][(quad * 4 + r) * 34 + t] = accK[nt][r];                 \
                    sqv[np][(quad * 4 + r) * 34 + t] = accQ[nt][r];                 \
                }                                                                   \
            }                                                                       \
        }

#define DO_PREFETCH(KF, QF)                                                         \
        if (ch <= NCH - 3) {                                                        \
            int tp = (ch + 2) * SCAN_C;                                             \
            _Pragma("unroll")                                                       \
            for (int nt = 0; nt < 2; ++nt)                                          \
                _Pragma("unroll")                                                   \
                for (int kk = 0; kk < 4; ++kk) {                                    \
                    size_t g = rowbase + (size_t)(tp + nt * 16 + L16) * HIDN + kk * 32 + quad * 8; \
                    KF[nt][kk] = *(const f16x8*)(k16 + g);                          \
                    QF[nt][kk] = *(const f16x8*)(q16 + g);                          \
                }                                                                   \
        }

        for (int ch = 0; ch < NCH; ++ch) {
            const int p = ch & 1;
            const int np = p ^ 1;
            const bool haveNext = (ch + 1 < NCH);

            // (0) fire-and-forget DMA staging for next slot + early avb loads
            float4 ar0, ar1; uint4 vr; float betr = 0.f;
            if (haveNext) {
                size_t gbn = (gmatbase + ch + 1) * 1024;
                size_t gbc = (gmatbase + ch) * 1024;
                const f16* gG = G_g  + gbn + lane * 8;
                const f16* gQ = KQ_g + gbn + lane * 8;
                const f16* gX = Gx_g + gbc + lane * 8;
                const f16* gY = Qx_g + gbc + lane * 8;
                gload_lds16(gG,       &G_lds[np][0]);
                gload_lds16(gG + 512, &G_lds[np][512]);
                gload_lds16(gQ,       &Q_lds[np][0]);
                gload_lds16(gQ + 512, &Q_lds[np][512]);
                gload_lds16(gX,       &Gx_lds[np][0]);
                gload_lds16(gX + 512, &Gx_lds[np][512]);
                gload_lds16(gY,       &Qx_lds[np][0]);
                gload_lds16(gY + 512, &Qx_lds[np][512]);
                const f16* gK = KT_g + (gmatbase + ch) * 4096 + lane * 8;
#pragma unroll
                for (int i = 0; i < 8; ++i)
                    gload_lds16(gK + i * 512, &KT_lds2[np][i * 512]);
                int tn = (ch + 1) * SCAN_C;
                size_t ga = rowbase + (size_t)(tn + t_av) * HIDN + v0 + halfsel * 8;
                ar0 = *(const float4*)(a_buf + ga);
                ar1 = *(const float4*)(a_buf + ga + 4);
                vr  = *(const uint4*)(v16 + ga);
                betr = beta_buf[((size_t)(b * TLEN) + tn + t_av) * NHEAD + h];
            }

            // (1) register prefetch into the idle regset (issue EARLY)
            if ((ch & 1) == 0) { DO_PREFETCH(kfB, qfB) }
            else               { DO_PREFETCH(kfA, qfA) }

            // (2) flush o of chunk ch-1 (coalesced float4 stores, drain hidden by MM)
            if (ch >= 1) {
                const int fp = (ch - 1) & 1;
                const int tprev = (ch - 1) * SCAN_C;
                const int tt = lane >> 1;
                const int hh = (lane & 1) * 8;
                float v8[8];
#pragma unroll
                for (int j = 0; j < 8; ++j) v8[j] = o_lds[fp][hh + j][tt];
                float4 f0; f0.x = v8[0]; f0.y = v8[1]; f0.z = v8[2]; f0.w = v8[3];
                float4 f1; f1.x = v8[4]; f1.y = v8[5]; f1.z = v8[6]; f1.w = v8[7];
                size_t ob = rowbase + (size_t)(tprev + tt) * HIDN + v0 + hh;
                *(float4*)(o_buf + ob)     = f0;
                *(float4*)(o_buf + ob + 4) = f1;
            }

            // (3) state update + stale-state MM with current regset
            if ((ch & 1) == 0) { DO_UPDATE_MM(kfA, qfA) }
            else               { DO_UPDATE_MM(kfB, qfB) }

            // (4) avb LDS writes (late — loads have had the whole chunk to land)
            if (haveNext) {
                const f16* vh = (const f16*)&vr;
                const float* aa0 = (const float*)&ar0;
                const float* aa1 = (const float*)&ar1;
#pragma unroll
                for (int e = 0; e < 4; ++e) {
                    float2 wv; wv.x = aa0[e]; wv.y = betr * (float)vh[e];
                    *(float2*)(&avb[np][(halfsel * 8 + e) * 68 + 2 * t_av]) = wv;
                    float2 wu; wu.x = aa1[e]; wu.y = betr * (float)vh[4 + e];
                    *(float2*)(&avb[np][(halfsel * 8 + 4 + e) * 68 + 2 * t_av]) = wu;
                }
                if (halfsel == 0) Bts[np][t_av] = betr;
            }
            __syncthreads();
        }
#undef DO_UPDATE_MM
#undef DO_PREFETCH

        // epilogue: flush o of the last chunk
        {
            const int fp = (NCH - 1) & 1;
            const int tprev = (NCH - 1) * SCAN_C;
            const int tt = lane >> 1;
            const int hh = (lane & 1) * 8;
            float v8[8];
#pragma unroll
            for (int j = 0; j < 8; ++j) v8[j] = o_lds[fp][hh + j][tt];
            float4 f0; f0.x = v8[0]; f0.y = v8[1]; f0.z = v8[2]; f0.w = v8[3];
            float4 f1; f1.x = v8[4]; f1.y = v8[5]; f1.z = v8[6]; f1.w = v8[7];
            size_t ob = rowbase + (size_t)(tprev + tt) * HIDN + v0 + hh;
            *(float4*)(o_buf + ob)     = f0;
            *(float4*)(o_buf + ob + 4) = f1;
        }
    } else {
        // =================== WAVE 0: serial critical path ===================
        __builtin_amdgcn_s_setprio(1);
        __syncthreads();   // B1 pair

        for (int ch = 0; ch < NCH; ++ch) {
            const int p = ch & 1;
            const int np = p ^ 1;

            // ---- cross-chunk fixup: sk = P*sk_stale + c~_{ch-1} . Gx (in place) ----
            {
                f16x8 caf = *(const f16x8*)(&c16s[np][L16 * 40 + quad * 8]);
                f32x4 fK[2], fQ[2];
#pragma unroll
                for (int nt = 0; nt < 2; ++nt) {
                    f16x8 bx = *(const f16x8*)(&Gx_lds[p][(nt * 16 + L16) * 32 + quad * 8]);
                    f16x8 by = *(const f16x8*)(&Qx_lds[p][(nt * 16 + L16) * 32 + quad * 8]);
                    fK[nt] = __builtin_amdgcn_mfma_f32_16x16x32_f16(caf, bx, (f32x4){0, 0, 0, 0}, 0, 0, 0);
                    fQ[nt] = __builtin_amdgcn_mfma_f32_16x16x32_f16(caf, by, (f32x4){0, 0, 0, 0}, 0, 0, 0);
                }
#pragma unroll
                for (int r = 0; r < 4; ++r) {
                    int vv = quad * 4 + r;
                    float Pv = PCs[np][vv];
#pragma unroll
                    for (int nt = 0; nt < 2; ++nt) {
                        int t = nt * 16 + L16;
                        skv[p][vv * 34 + t] = fmaf(Pv, skv[p][vv * 34 + t], fK[nt][r]);
                        sqv[p][vv * 34 + t] = fmaf(Pv, sqv[p][vv * 34 + t], fQ[nt][r]);
                    }
                }
            }

            // ---- triangular solve: 4 windows of {bulk LDS gather -> 4 reg-only iters} ----
            {
                f16x2 c0, c1, c2, c3;
                c0.x = (f16)0.f; c0.y = (f16)0.f; c1 = c0; c2 = c0; c3 = c0;
                float P = 1.f;
                union RowU { uint4 u4; f16x2 h2[4]; };

#pragma unroll
                for (int wnd = 0; wnd < 4; ++wnd) {
                    const int tw = wnd * 8;
                    uint4  bg0[4], bg1[4], bh0[4], bh1[4];
                    float2 bskp[4], bsqp[4], bbtp[4];
                    float4 bab4[4];
                    float  bkq00[4], bg01[4];
                    f16x2  bdq[4];
#pragma unroll
                    for (int i = 0; i < 4; ++i) {
                        const int t = tw + i * 2;
                        bg0[i] = *(const uint4*)(&G_lds[p][t * 32 + li * 8]);
                        bg1[i] = *(const uint4*)(&G_lds[p][(t + 1) * 32 + li * 8]);
                        bh0[i] = *(const uint4*)(&Q_lds[p][t * 32 + li * 8]);
                        bh1[i] = *(const uint4*)(&Q_lds[p][(t + 1) * 32 + li * 8]);
                        bskp[i] = *(const float2*)(&skv[p][vl * 34 + t]);
                        bsqp[i] = *(const float2*)(&sqv[p][vl * 34 + t]);
                        bab4[i] = *(const float4*)(&avb[p][vl * 68 + 2 * t]);
                        bbtp[i] = *(const float2*)(&Bts[p][t]);
                        bkq00[i] = (float)Q_lds[p][t * 32 + t];
                        bdq[i]  = *(const f16x2*)(&Q_lds[p][(t + 1) * 32 + t]);
                        bg01[i] = (float)G_lds[p][(t + 1) * 32 + t];
                    }
#pragma unroll
                    for (int i = 0; i < 4; ++i) {
                        const int t = tw + i * 2;
                        RowU g0u, g1u, h0u, h1u;
                        g0u.u4 = bg0[i]; g1u.u4 = bg1[i];
                        h0u.u4 = bh0[i]; h1u.u4 = bh1[i];
                        float2 skp = bskp[i], sqp = bsqp[i], btp = bbtp[i];
                        float4 ab4 = bab4[i];
                        float kq00 = bkq00[i], g01 = bg01[i];
                        f16x2 dq = bdq[i];

                        float pG  = fdot2_(c0, g0u.h2[0], fdot2_(c1, g0u.h2[1], 0.f))
                                  + fdot2_(c2, g0u.h2[2], fdot2_(c3, g0u.h2[3], 0.f));
                        float pG1 = fdot2_(c0, g1u.h2[0], fdot2_(c1, g1u.h2[1], 0.f))
                                  + fdot2_(c2, g1u.h2[2], fdot2_(c3, g1u.h2[3], 0.f));
                        float pO  = fdot2_(c0, h0u.h2[0], fdot2_(c1, h0u.h2[1], 0.f))
                                  + fdot2_(c2, h0u.h2[2], fdot2_(c3, h0u.h2[3], 0.f));
                        float pO1 = fdot2_(c0, h1u.h2[0], fdot2_(c1, h1u.h2[1], 0.f))
                                  + fdot2_(c2, h1u.h2[2], fdot2_(c3, h1u.h2[3], 0.f));
                        int tmp;
                        tmp = __builtin_amdgcn_update_dpp(0, __float_as_int(pG),  0xB1, 0xF, 0xF, true); pG  += __int_as_float(tmp);
                        tmp = __builtin_amdgcn_update_dpp(0, __float_as_int(pG1), 0xB1, 0xF, 0xF, true); pG1 += __int_as_float(tmp);
                        tmp = __builtin_amdgcn_update_dpp(0, __float_as_int(pO),  0xB1, 0xF, 0xF, true); pO  += __int_as_float(tmp);
                        tmp = __builtin_amdgcn_update_dpp(0, __float_as_int(pO1), 0xB1, 0xF, 0xF, true); pO1 += __int_as_float(tmp);
                        tmp = __builtin_amdgcn_update_dpp(0, __float_as_int(pG),  0x4E, 0xF, 0xF, true); pG  += __int_as_float(tmp);
                        tmp = __builtin_amdgcn_update_dpp(0, __float_as_int(pG1), 0x4E, 0xF, 0xF, true); pG1 += __int_as_float(tmp);
                        tmp = __builtin_amdgcn_update_dpp(0, __float_as_int(pO),  0x4E, 0xF, 0xF, true); pO  += __int_as_float(tmp);
                        tmp = __builtin_amdgcn_update_dpp(0, __float_as_int(pO1), 0x4E, 0xF, 0xF, true); pO1 += __int_as_float(tmp);

                        float a0 = ab4.x, bv0 = ab4.y, a1 = ab4.z, bv1 = ab4.w;
                        float bt0 = btp.x, bt1 = btp.y;
                        float sk0 = skp.x * ISSC, sk1 = skp.y * ISSC;
                        float sq0 = sqp.x * ISSC, sq1 = sqp.y * ISSC;
                        float kq01 = (float)dq.x, kq11 = (float)dq.y;

                        // step t
                        float x0 = fmaf(P, sk0, pG);
                        float u0 = fmaf(-bt0, x0, bv0);
                        float P0 = P * a0;
                        float o0 = fmaf(a0, pO, u0 * kq00);
                        o0 = fmaf(P0, sq0, o0);
                        // step t+1 (cross-terms via u0 explicitly)
                        float accGv = fmaf(a0, pG1, u0 * g01);
                        float x1 = fmaf(P0, sk1, accGv);
                        float u1 = fmaf(-bt1, x1, bv1);
                        float P1 = P0 * a1;
                        float accOv = fmaf(a0, pO1, u0 * kq01);
                        float o1 = fmaf(a1, accOv, u1 * kq11);
                        o1 = fmaf(P1, sq1, o1);

                        float aa = a0 * a1;
                        f16 aah = (f16)aa;
                        f16x2 aa2; aa2.x = aah; aa2.y = aah;
                        c0 *= aa2; c1 *= aa2; c2 *= aa2; c3 *= aa2;
                        if (li == (t >> 3)) {
                            f16x2 un; un.x = (f16)(u0 * a1); un.y = (f16)u1;
                            int sel = (t & 7) >> 1;
                            if (sel == 0) c0 = un; else if (sel == 1) c1 = un;
                            else if (sel == 2) c2 = un; else c3 = un;
                        }
                        P = P1;
                        if (li == 0) {
                            float2 o2; o2.x = o0; o2.y = o1;
                            *(float2*)(&o_lds[p][vl][t]) = o2;
                        }
                    }
                }
                f16 s16 = (f16)SSC;
                f16x2 ss2; ss2.x = s16; ss2.y = s16;
                union { f16x2 h2[4]; uint4 u4; } pc;
                pc.h2[0] = c0 * ss2; pc.h2[1] = c1 * ss2; pc.h2[2] = c2 * ss2; pc.h2[3] = c3 * ss2;
                *(uint4*)(&c16s[p][vl * 40 + li * 8]) = pc.u4;
                if (li == 0) PCs[p][vl] = P;
            }
            __syncthreads();
        }
    }
}

// ---------------------------------------------------------------------------
// K6: LayerNorm over head dim, * g, -> f16 for output GEMM
__global__ __launch_bounds__(256) void ln_gate_kernel(
    const float* __restrict__ o_buf, const f16* __restrict__ g16,
    const float* __restrict__ lng, const float* __restrict__ lnb,
    f16* __restrict__ og16)
{
    int row = blockIdx.x;
    int h = threadIdx.x >> 5, lane = threadIdx.x & 31;
    size_t base = (size_t)row * HIDN + h * HD + lane * 4;
    float4 x = *(const float4*)(o_buf + base);
    float s  = x.x + x.y + x.z + x.w;
    float sq = x.x * x.x + x.y * x.y + x.z * x.z + x.w * x.w;
#pragma unroll
    for (int m = 1; m <= 16; m <<= 1) {
        s  += __shfl_xor(s, m);
        sq += __shfl_xor(sq, m);
    }
    float mu  = s * (1.0f / 128.0f);
    float var = sq * (1.0f / 128.0f) - mu * mu;
    float inv = 1.0f / sqrtf(var + 1e-5f);
    int d = lane * 4;
    const float* xp = (const float*)&x;
    union { f16 h4[4]; uint2 u; } pk;
#pragma unroll
    for (int j = 0; j < 4; ++j) {
        float on = (xp[j] - mu) * inv * lng[d + j] + lnb[d + j];
        pk.h4[j] = (f16)(on * (float)g16[base + j]);
    }
    *(uint2*)(og16 + base) = pk.u;
}

// ---------------------------------------------------------------------------
extern "C" void kernel_launch(void* const* d_in, const int* in_sizes, int n_in,
                              void* d_out, int out_size, void* d_ws, size_t ws_size,
                              hipStream_t stream)
{
    (void)in_sizes; (void)n_in; (void)out_size; (void)ws_size;
    const float* x   = (const float*)d_in[0];
    const float* Wq  = (const float*)d_in[1];
    const float* Wk  = (const float*)d_in[2];
    const float* Wv  = (const float*)d_in[3];
    const float* Wa  = (const float*)d_in[4];
    const float* ba  = (const float*)d_in[5];
    const float* Wb  = (const float*)d_in[6];
    const float* bb  = (const float*)d_in[7];
    const float* Wg  = (const float*)d_in[8];
    const float* Wo  = (const float*)d_in[9];
    const float* cqw = (const float*)d_in[10];
    const float* cqb = (const float*)d_in[11];
    const float* ckw = (const float*)d_in[12];
    const float* ckb = (const float*)d_in[13];
    const float* cvw = (const float*)d_in[14];
    const float* cvb = (const float*)d_in[15];
    const float* lng = (const float*)d_in[16];
    const float* lnb = (const float*)d_in[17];
    float* out = (float*)d_out;

    char* ws = (char*)d_ws;
    f16*   x16      = (f16*)(ws + 0);                 //  8,388,608 B
    f16*   WT       = (f16*)(ws + 8388608);           // 12,582,912 B
    f16*   qkvh     = (f16*)(ws + 20971520);          // 25,165,824 B (reused by gram outputs)
    f16*   qkv16    = (f16*)(ws + 46137344);          // 25,165,824 B (f16 q,k,v post-conv)
    float* a_buf    = (float*)(ws + 96468992);        // 16,777,216 B
    f16*   g16      = (f16*)(ws + 113246208);         //  8,388,608 B
    float* beta_buf = (float*)(ws + 121634816);       //    131,072 B
    float* o_buf    = (float*)(ws + 121765888);       // 16,777,216 B
    f16*   og16     = (f16*)(ws + 138543104);         //  8,388,608 B

    // gram pre-pass outputs reuse the (dead after conv) qkvh region: 16 MB <= 24 MB
    f16* G_g  = qkvh;                 // 16*64*1024 f16 = 2 MB
    f16* KQ_g = qkvh + 1048576;       // 2 MB
    f16* Gx_g = qkvh + 2097152;       // 2 MB
    f16* Qx_g = qkvh + 3145728;       // 2 MB
    f16* KT_g = qkvh + 4194304;       // 16*64*4096 f16 = 8 MB

    convert_x_kernel<<<dim3(4096), dim3(256), 0, stream>>>(x, x16);
    transpose_convert_kernel<<<dim3(32, 32, 6), dim3(256), 0, stream>>>(Wq, Wk, Wv, Wa, Wg, Wo, WT);
    gemm_f16<0><<<dim3(40, 32), dim3(256), 0, stream>>>(x16, WT, nullptr, qkvh, a_buf, g16, ba);
    beta_kernel<<<dim3(4096), dim3(256), 0, stream>>>(x, Wb, bb, beta_buf);
    conv_silu_kernel<<<dim3(4096, 3), dim3(256), 0, stream>>>(qkvh, cqw, cqb, ckw, ckb, cvw, cvb, qkv16);
    gram_kernel<<<dim3(NCH, 16), dim3(64), 0, stream>>>(
        qkv16, qkv16 + XELEMS, G_g, KQ_g, Gx_g, Qx_g, KT_g);
    scan2_kernel<<<dim3(16, 8), dim3(128), 0, stream>>>(
        qkv16, qkv16 + XELEMS, qkv16 + 2 * (size_t)XELEMS, a_buf, beta_buf,
        G_g, KQ_g, Gx_g, Qx_g, KT_g, o_buf);
    ln_gate_kernel<<<dim3(4096), dim3(256), 0, stream>>>(o_buf, g16, lng, lnb, og16);
    gemm_f16<1><<<dim3(8, 32), dim3(256), 0, stream>>>(og16, WT + 5 * (size_t)MAT_ELEMS, out,
                                                       nullptr, nullptr, nullptr, nullptr);
}

// Round 9
// 508.151 us; speedup vs baseline: 1.4143x; 1.0085x over previous
//
#include <hip/hip_runtime.h>
#include <hip/hip_bf16.h>
#include <cstdint>
#include <cstddef>

// Problem dims (fixed)
#define BATCH 2
#define TLEN  2048
#define NHEAD 8
#define HD    128
#define HIDN  1024
#define MTOT  4096          // BATCH*TLEN
#define MAT_ELEMS 1048576   // 1024*1024
#define XELEMS 4194304      // 4096*1024
#define SCAN_C 32
#define NCH    64           // TLEN / SCAN_C
#define SSC  1024.0f
#define ISSC 0.0009765625f

typedef _Float16 f16;
typedef _Float16 f16x2 __attribute__((ext_vector_type(2)));
typedef _Float16 f16x8 __attribute__((ext_vector_type(8)));
typedef float    f32x4 __attribute__((ext_vector_type(4)));

__device__ __forceinline__ float sigmoidf_(float v) { return 1.0f / (1.0f + __expf(-v)); }

// f16x2 dot with f32 accumulate: v_dot2_f32_f16 (exact products, f32 accum)
__device__ __forceinline__ float fdot2_(f16x2 a, f16x2 b, float c)
{
#if __has_builtin(__builtin_amdgcn_fdot2)
    return __builtin_amdgcn_fdot2(a, b, c, false);
#else
    return fmaf((float)a.x, (float)b.x, fmaf((float)a.y, (float)b.y, c));
#endif
}

// async global->LDS DMA: 16B per lane, LDS dest = wave-uniform base + lane*16B
__device__ __forceinline__ void gload_lds16(const f16* g, f16* l)
{
    __builtin_amdgcn_global_load_lds(
        (const __attribute__((address_space(1))) uint32_t*)(g),
        (__attribute__((address_space(3))) uint32_t*)(l), 16, 0, 0);
}

// ---------------------------------------------------------------------------
// K0: fused prep — transpose-convert 6 weight mats (blocks 0..6143),
// convert x->f16 (blocks 6144..10239), beta (blocks 10240..14335).
// All three depend only on kernel inputs -> one launch, full concurrency.
__global__ __launch_bounds__(256) void prep_kernel(
    const float* __restrict__ x,
    const float* __restrict__ Wq, const float* __restrict__ Wk, const float* __restrict__ Wv,
    const float* __restrict__ Wa, const float* __restrict__ Wg, const float* __restrict__ Wo,
    const float* __restrict__ Wb, const float* __restrict__ bb,
    f16* __restrict__ x16, f16* __restrict__ WT, float* __restrict__ beta_buf)
{
    __shared__ float tile[32][33];
    int bid = blockIdx.x;
    if (bid < 6144) {
        // ---- transpose_convert: WT[mat][n][k] = (f16)W[k][n] ----
        int mat = bid >> 10;
        int within = bid & 1023;
        int n0 = (within & 31) * 32;
        int k0 = (within >> 5) * 32;
        const float* W = (mat == 0) ? Wq : (mat == 1) ? Wk : (mat == 2) ? Wv
                       : (mat == 3) ? Wa : (mat == 4) ? Wg : Wo;
        int tr = threadIdx.x >> 3;
        int tc = (threadIdx.x & 7) * 4;
        float4 vin = *(const float4*)(W + (size_t)(k0 + tr) * HIDN + n0 + tc);
        tile[tr][tc + 0] = vin.x; tile[tr][tc + 1] = vin.y;
        tile[tr][tc + 2] = vin.z; tile[tr][tc + 3] = vin.w;
        __syncthreads();
        f16* dst = WT + (size_t)(mat * HIDN + n0 + tr) * HIDN + k0 + tc;
        union { f16 h[4]; uint2 u; } pk;
        pk.h[0] = (f16)tile[tc + 0][tr]; pk.h[1] = (f16)tile[tc + 1][tr];
        pk.h[2] = (f16)tile[tc + 2][tr]; pk.h[3] = (f16)tile[tc + 3][tr];
        *(uint2*)dst = pk.u;
    } else if (bid < 6144 + 4096) {
        // ---- convert x -> f16 ----
        int i = ((bid - 6144) * 256 + threadIdx.x) * 4;
        float4 v = *(const float4*)(x + i);
        union { f16 h[4]; uint2 u; } pk;
        pk.h[0] = (f16)v.x; pk.h[1] = (f16)v.y; pk.h[2] = (f16)v.z; pk.h[3] = (f16)v.w;
        *(uint2*)(x16 + i) = pk.u;
    } else {
        // ---- beta = sigmoid(x @ Wb + bb), fp32 exact ----
        int row = bid - 10240;
        int h = threadIdx.x >> 5, lane = threadIdx.x & 31;
        const float* xr = x + (size_t)row * HIDN;
        float part = 0.f;
        for (int i = lane; i < HIDN; i += 32)
            part += xr[i] * Wb[i * NHEAD + h];
#pragma unroll
        for (int m = 1; m <= 16; m <<= 1) part += __shfl_xor(part, m);
        if (lane == 0)
            beta_buf[(size_t)row * NHEAD + h] = sigmoidf_(part + bb[h]);
    }
}

// ---------------------------------------------------------------------------
// K2/K7: f16 MFMA GEMM, C = A[M,1024] @ BT[n][k]^T, 128x128 tile, BK=32.
// m97 structure: global_load_lds width=16 staging into linear [128][32] tiles.
// XCD-aware bijective workgroup swizzle (T1).
template <int MODE>
__global__ __launch_bounds__(256) void gemm_f16(
    const f16* __restrict__ A, const f16* __restrict__ BT,
    float* __restrict__ out_f32,
    f16* __restrict__ qkv_hat, float* __restrict__ a_buf, f16* __restrict__ g16,
    const float* __restrict__ ba)
{
    __shared__ __align__(16) f16 As[128][32];
    __shared__ __align__(16) f16 Bs[128][32];

    // XCD swizzle (bijective since nwg % 8 == 0 for both launches)
    int nwg = gridDim.x * gridDim.y;
    int wg  = blockIdx.y * gridDim.x + blockIdx.x;
    int qq  = nwg >> 3;
    int swz = (wg & 7) * qq + (wg >> 3);
    int bx  = swz % gridDim.x;
    int by  = swz / gridDim.x;

    int m0 = by * 128;
    int n0 = bx * 128;
    int tid = threadIdx.x;
    int w = tid >> 6, lane = tid & 63;
    int L16 = lane & 15, quad = lane >> 4;
    int wm = (w >> 1) * 64, wn = (w & 1) * 64;

    f32x4 acc[4][4];
#pragma unroll
    for (int i = 0; i < 4; ++i)
#pragma unroll
        for (int j = 0; j < 4; ++j) acc[i][j] = (f32x4){0.f, 0.f, 0.f, 0.f};

    int ldr = tid >> 2;            // 0..63
    int ldc = (tid & 3) * 8;
    f16* asb0 = &As[0][0]  + w * 512;
    f16* asb1 = &As[64][0] + w * 512;
    f16* bsb0 = &Bs[0][0]  + w * 512;
    f16* bsb1 = &Bs[64][0] + w * 512;

    for (int k0 = 0; k0 < 1024; k0 += 32) {
        __syncthreads();
        gload_lds16(A  + (size_t)(m0 + ldr) * HIDN + k0 + ldc,      asb0);
        gload_lds16(A  + (size_t)(m0 + ldr + 64) * HIDN + k0 + ldc, asb1);
        gload_lds16(BT + (size_t)(n0 + ldr) * HIDN + k0 + ldc,      bsb0);
        gload_lds16(BT + (size_t)(n0 + ldr + 64) * HIDN + k0 + ldc, bsb1);
        __syncthreads();
        f16x8 af[4], bf[4];
#pragma unroll
        for (int i = 0; i < 4; ++i) {
            af[i] = *(const f16x8*)(&As[wm + i * 16 + L16][quad * 8]);
            bf[i] = *(const f16x8*)(&Bs[wn + i * 16 + L16][quad * 8]);
        }
#pragma unroll
        for (int i = 0; i < 4; ++i)
#pragma unroll
            for (int j = 0; j < 4; ++j)
                acc[i][j] = __builtin_amdgcn_mfma_f32_16x16x32_f16(af[i], bf[j], acc[i][j], 0, 0, 0);
    }

#pragma unroll
    for (int i = 0; i < 4; ++i) {
#pragma unroll
        for (int j = 0; j < 4; ++j) {
            f32x4 c = acc[i][j];
            int mbase = m0 + wm + i * 16 + quad * 4;
            int n = n0 + wn + j * 16 + L16;
            if (MODE == 1) {
#pragma unroll
                for (int r = 0; r < 4; ++r)
                    out_f32[(size_t)(mbase + r) * HIDN + n] = c[r];
            } else {
                int mat = n >> 10;
                int nn = n & 1023;
                if (mat < 3) {
#pragma unroll
                    for (int r = 0; r < 4; ++r)
                        qkv_hat[(size_t)mat * XELEMS + (size_t)(mbase + r) * HIDN + nn] = (f16)c[r];
                } else if (mat == 3) {
                    float bav = ba[nn];
#pragma unroll
                    for (int r = 0; r < 4; ++r)
                        a_buf[(size_t)(mbase + r) * HIDN + nn] = sigmoidf_(c[r] + bav);
                } else {
#pragma unroll
                    for (int r = 0; r < 4; ++r)
                        g16[(size_t)(mbase + r) * HIDN + nn] = (f16)sigmoidf_(c[r]);
                }
            }
        }
    }
}

// ---------------------------------------------------------------------------
// K4: causal depthwise conv (K=4) + SiLU (+ scale for k), f16 output.
__global__ __launch_bounds__(256) void conv_silu_kernel(
    const f16* __restrict__ qkv_hat,
    const float* __restrict__ cqw, const float* __restrict__ cqb,
    const float* __restrict__ ckw, const float* __restrict__ ckb,
    const float* __restrict__ cvw, const float* __restrict__ cvb,
    f16* __restrict__ qkv16)
{
    int z = blockIdx.y;
    int row = blockIdx.x;
    int tloc = row & (TLEN - 1);
    int c4 = threadIdx.x * 4;
    const f16* src = qkv_hat + (size_t)z * XELEMS;
    const float* w  = (z == 0) ? cqw : (z == 1) ? ckw : cvw;
    const float* bi = (z == 0) ? cqb : (z == 1) ? ckb : cvb;

    float xv[4][4];
#pragma unroll
    for (int j = 0; j < 4; ++j) {
        int tt = tloc - 3 + j;
        if (tt >= 0) {
            const f16* p = src + (size_t)(row - 3 + j) * HIDN + c4;
            xv[j][0] = (float)p[0]; xv[j][1] = (float)p[1];
            xv[j][2] = (float)p[2]; xv[j][3] = (float)p[3];
        } else {
            xv[j][0] = xv[j][1] = xv[j][2] = xv[j][3] = 0.f;
        }
    }
    float scale = (z == 1) ? 0.08838834764831845f : 1.0f;  // 128^-0.5 for k
    union { f16 h[4]; uint2 u; } pk;
#pragma unroll
    for (int cc = 0; cc < 4; ++cc) {
        float4 wc = *(const float4*)(w + (size_t)(c4 + cc) * 4);
        float acc = bi[c4 + cc] + wc.x * xv[0][cc] + wc.y * xv[1][cc]
                                 + wc.z * xv[2][cc] + wc.w * xv[3][cc];
        pk.h[cc] = (f16)(acc * sigmoidf_(acc) * scale);
    }
    *(uint2*)(qkv16 + (size_t)z * XELEMS + (size_t)row * HIDN + c4) = pk.u;
}

// ---------------------------------------------------------------------------
// K4b: gram pre-pass. Per (chunk, bh): all state-INDEPENDENT chunk matrices.
// K^T store now goes through an LDS transpose stage -> coalesced dwordx4
// global stores (was 64 scalar 2B stores/lane).
__global__ __launch_bounds__(64) void gram_kernel(
    const f16* __restrict__ q16, const f16* __restrict__ k16,
    f16* __restrict__ G_g, f16* __restrict__ KQ_g,
    f16* __restrict__ Gx_g, f16* __restrict__ Qx_g, f16* __restrict__ KT_g)
{
    __shared__ __align__(16) f16 kt_s[32][138];  // [t][k], stride 138 -> 2-way bank alias (free)
    int ch = blockIdx.x;
    int bh = blockIdx.y;
    int b = bh >> 3, h = bh & 7;
    int lane = threadIdx.x;
    int L16 = lane & 15, quad = lane >> 4;
    size_t rowbase = (size_t)(b * TLEN) * HIDN + h * HD;
    int t0 = ch * SCAN_C;
    bool hasNext = (ch + 1 < NCH);

    union ZU { uint4 u; f16x8 v; };
    ZU zz; zz.u = (uint4){0, 0, 0, 0};

    f16x8 kc[2][4], qc[2][4], kn[2][4], qn[2][4];
#pragma unroll
    for (int nt = 0; nt < 2; ++nt)
#pragma unroll
        for (int kk = 0; kk < 4; ++kk) {
            size_t g = rowbase + (size_t)(t0 + nt * 16 + L16) * HIDN + kk * 32 + quad * 8;
            kc[nt][kk] = *(const f16x8*)(k16 + g);
            qc[nt][kk] = *(const f16x8*)(q16 + g);
            if (hasNext) {
                kn[nt][kk] = *(const f16x8*)(k16 + g + (size_t)SCAN_C * HIDN);
                qn[nt][kk] = *(const f16x8*)(q16 + g + (size_t)SCAN_C * HIDN);
            } else {
                kn[nt][kk] = zz.v; qn[nt][kk] = zz.v;
            }
        }

    // stage K chunk into LDS [t][k] for the transposed coalesced store
#pragma unroll
    for (int nt = 0; nt < 2; ++nt)
#pragma unroll
        for (int kk = 0; kk < 4; ++kk)
            *(f16x8*)(&kt_s[nt * 16 + L16][kk * 32 + quad * 8]) = kc[nt][kk];

    f32x4 aG[2][2], aKQ[2][2], aGx[2][2], aQx[2][2];
#pragma unroll
    for (int i = 0; i < 2; ++i)
#pragma unroll
        for (int j = 0; j < 2; ++j) {
            aG[i][j] = (f32x4){0, 0, 0, 0}; aKQ[i][j] = (f32x4){0, 0, 0, 0};
            aGx[i][j] = (f32x4){0, 0, 0, 0}; aQx[i][j] = (f32x4){0, 0, 0, 0};
        }
#pragma unroll
    for (int kk = 0; kk < 4; ++kk)
#pragma unroll
        for (int mt = 0; mt < 2; ++mt)
#pragma unroll
            for (int nt = 0; nt < 2; ++nt) {
                aG[mt][nt]  = __builtin_amdgcn_mfma_f32_16x16x32_f16(kc[mt][kk], kc[nt][kk], aG[mt][nt], 0, 0, 0);
                aKQ[mt][nt] = __builtin_amdgcn_mfma_f32_16x16x32_f16(kc[mt][kk], qc[nt][kk], aKQ[mt][nt], 0, 0, 0);
                aGx[mt][nt] = __builtin_amdgcn_mfma_f32_16x16x32_f16(kc[mt][kk], kn[nt][kk], aGx[mt][nt], 0, 0, 0);
                aQx[mt][nt] = __builtin_amdgcn_mfma_f32_16x16x32_f16(kc[mt][kk], qn[nt][kk], aQx[mt][nt], 0, 0, 0);
            }

    size_t gb = ((size_t)bh * NCH + ch) * 1024;
#pragma unroll
    for (int nt = 0; nt < 2; ++nt) {
        int t = nt * 16 + L16;
#pragma unroll
        for (int mt = 0; mt < 2; ++mt) {
            union { f16 e[4]; uint2 u2; } pg, pq, px, py;
#pragma unroll
            for (int r = 0; r < 4; ++r) {
                pg.e[r] = (f16)aG[mt][nt][r];
                pq.e[r] = (f16)aKQ[mt][nt][r];
                px.e[r] = (f16)aGx[mt][nt][r];
                py.e[r] = (f16)aQx[mt][nt][r];
            }
            *(uint2*)(G_g  + gb + t * 32 + mt * 16 + quad * 4) = pg.u2;
            *(uint2*)(KQ_g + gb + t * 32 + mt * 16 + quad * 4) = pq.u2;
            *(uint2*)(Gx_g + gb + t * 32 + mt * 16 + quad * 4) = px.u2;
            *(uint2*)(Qx_g + gb + t * 32 + mt * 16 + quad * 4) = py.u2;
        }
    }

    // K^T store: coalesced. lane writes 8x dwordx4; store s covers
    // flat = s*512 + lane*8  ->  k = s*16 + (lane>>2), t = (lane&3)*8 .. +8
    __syncthreads();
    size_t kb = ((size_t)bh * NCH + ch) * 4096;
    int kcol = lane >> 2;
    int tbase = (lane & 3) * 8;
#pragma unroll
    for (int s = 0; s < 8; ++s) {
        union { f16 hh[8]; uint4 u; } pk;
        int k = s * 16 + kcol;
#pragma unroll
        for (int e = 0; e < 8; ++e) pk.hh[e] = kt_s[tbase + e][k];
        *(uint4*)(KT_g + kb + (size_t)s * 512 + lane * 8) = pk.u;
    }
}

// ---------------------------------------------------------------------------
// K5: producer/consumer chunked delta-rule scan (R6 structure — best verified).
//  wave0 = serial critical path: cross-chunk fixup (4 MFMA) + triangular solve
//          as 4 windows/chunk: bulk-gather ALL LDS inputs for 4 iterations
//          back-to-back, then 4 iterations of register-resident compute.
//  wave1 = state update + stale-state MM + DMA staging + prefetch + o-flush.
__global__ __launch_bounds__(128, 1) void scan2_kernel(
    const f16* __restrict__ q16, const f16* __restrict__ k16, const f16* __restrict__ v16,
    const float* __restrict__ a_buf, const float* __restrict__ beta_buf,
    const f16* __restrict__ G_g, const f16* __restrict__ KQ_g,
    const f16* __restrict__ Gx_g, const f16* __restrict__ Qx_g, const f16* __restrict__ KT_g,
    float* __restrict__ o_buf)
{
    __shared__ __align__(16) float Sp[16 * 132];      // fp32 master state, wave1-owned
    __shared__ __align__(16) f16   Sp16[16 * 136];    // f16 shadow, wave1-owned
    __shared__ __align__(16) f16   KT_lds2[2][4096];  // K^T double buffer (DMA dest)
    __shared__ __align__(16) f16   G_lds[2][1024];    // G[t*32+tau]
    __shared__ __align__(16) f16   Q_lds[2][1024];    // KQ[t*32+tau]
    __shared__ __align__(16) f16   Gx_lds[2][1024];   // cross gram
    __shared__ __align__(16) f16   Qx_lds[2][1024];
    __shared__ __align__(16) float skv[2][16 * 34];   // [v][t]; w1 writes stale, w0 fixes
    __shared__ __align__(16) float sqv[2][16 * 34];
    __shared__ __align__(16) float avb[2][16 * 68];   // [v][2t + {a, beta*v}]
    __shared__ __align__(16) float Bts[2][32];
    __shared__ __align__(16) f16   c16s[2][16 * 40];  // c~ (SSC-scaled)
    __shared__ __align__(16) float PCs[2][16];        // per-v chunk decay product
    __shared__ __align__(16) float o_lds[2][16][34];  // o staging [v][t], w0 -> w1 flush

    const int tid = threadIdx.x;
    const int wid = tid >> 6;
    const int lane = tid & 63;
    const int L16 = lane & 15, quad = lane >> 4;
    const int vl = lane >> 2, li = lane & 3;
    const int t_av = lane >> 1, halfsel = lane & 1;

    const int bh = blockIdx.x;
    const int b = bh >> 3, h = bh & 7;
    const int v0 = blockIdx.y * 16;
    const size_t rowbase = (size_t)(b * TLEN) * HIDN + h * HD;
    const size_t gmatbase = (size_t)bh * NCH;

    // ---- zero all LDS (one-time) ----
    {
        for (int i = tid; i < 16 * 132; i += 128) Sp[i] = 0.f;
        uint32_t* z;
        z = (uint32_t*)Sp16;    for (int i = tid; i < 16 * 136 / 2; i += 128) z[i] = 0u;
        z = (uint32_t*)KT_lds2; for (int i = tid; i < 2 * 4096 / 2; i += 128) z[i] = 0u;
        z = (uint32_t*)G_lds;   for (int i = tid; i < 1024;          i += 128) z[i] = 0u;
        z = (uint32_t*)Q_lds;   for (int i = tid; i < 1024;          i += 128) z[i] = 0u;
        z = (uint32_t*)Gx_lds;  for (int i = tid; i < 1024;          i += 128) z[i] = 0u;
        z = (uint32_t*)Qx_lds;  for (int i = tid; i < 1024;          i += 128) z[i] = 0u;
        z = (uint32_t*)skv;     for (int i = tid; i < 2 * 16 * 34;   i += 128) z[i] = 0u;
        z = (uint32_t*)sqv;     for (int i = tid; i < 2 * 16 * 34;   i += 128) z[i] = 0u;
        z = (uint32_t*)avb;     for (int i = tid; i < 2 * 16 * 68;   i += 128) z[i] = 0u;
        z = (uint32_t*)Bts;     for (int i = tid; i < 2 * 32;        i += 128) z[i] = 0u;
        z = (uint32_t*)c16s;    for (int i = tid; i < 2 * 16 * 40 / 2; i += 128) z[i] = 0u;
        z = (uint32_t*)PCs;     for (int i = tid; i < 2 * 16;        i += 128) z[i] = 0u;
    }
    __syncthreads();

    if (wid == 1) {
        // =================== WAVE 1: state keeper / stager ===================
        f16x8 kfA[2][4], qfA[2][4], kfB[2][4], qfB[2][4];

        // ---- prologue: stage slot-0 consumables (reg path, one-time) ----
        {
            size_t gb0 = gmatbase * 1024;
            *(uint4*)(&G_lds[0][lane * 16])     = *(const uint4*)(G_g  + gb0 + lane * 16);
            *(uint4*)(&G_lds[0][lane * 16 + 8]) = *(const uint4*)(G_g  + gb0 + lane * 16 + 8);
            *(uint4*)(&Q_lds[0][lane * 16])     = *(const uint4*)(KQ_g + gb0 + lane * 16);
            *(uint4*)(&Q_lds[0][lane * 16 + 8]) = *(const uint4*)(KQ_g + gb0 + lane * 16 + 8);
            size_t ga = rowbase + (size_t)t_av * HIDN + v0 + halfsel * 8;
            float4 ar0 = *(const float4*)(a_buf + ga);
            float4 ar1 = *(const float4*)(a_buf + ga + 4);
            uint4  vr  = *(const uint4*)(v16 + ga);
            float betr = beta_buf[((size_t)(b * TLEN) + t_av) * NHEAD + h];
            const f16* vh = (const f16*)&vr;
            const float* aa0 = (const float*)&ar0;
            const float* aa1 = (const float*)&ar1;
#pragma unroll
            for (int e = 0; e < 4; ++e) {
                float2 wv; wv.x = aa0[e]; wv.y = betr * (float)vh[e];
                *(float2*)(&avb[0][(halfsel * 8 + e) * 68 + 2 * t_av]) = wv;
                float2 wu; wu.x = aa1[e]; wu.y = betr * (float)vh[4 + e];
                *(float2*)(&avb[0][(halfsel * 8 + 4 + e) * 68 + 2 * t_av]) = wu;
            }
            if (halfsel == 0) Bts[0][t_av] = betr;
        }
        __syncthreads();   // B1

#define DO_UPDATE_MM(KF, QF)                                                        \
        if (ch >= 1 && ch <= NCH - 2) {                                             \
            f16x8 ca = *(const f16x8*)(&c16s[np][L16 * 40 + quad * 8]);             \
            float pc = PCs[np][L16];                                                \
            _Pragma("unroll")                                                       \
            for (int kt = 0; kt < 8; ++kt) {                                        \
                f16x8 bu = *(const f16x8*)(&KT_lds2[p][(kt * 16 + L16) * 32 + quad * 8]); \
                f32x4 d = __builtin_amdgcn_mfma_f32_16x16x32_f16(bu, ca, (f32x4){0, 0, 0, 0}, 0, 0, 0); \
                int idx = L16 * 132 + kt * 16 + quad * 4;                           \
                float4 s = *(const float4*)(&Sp[idx]);                              \
                s.x = fmaf(pc, s.x, d[0]);                                          \
                s.y = fmaf(pc, s.y, d[1]);                                          \
                s.z = fmaf(pc, s.z, d[2]);                                          \
                s.w = fmaf(pc, s.w, d[3]);                                          \
                *(float4*)(&Sp[idx]) = s;                                           \
                union { f16 e[4]; uint2 u2; } ph;                                   \
                ph.e[0] = (f16)s.x; ph.e[1] = (f16)s.y;                             \
                ph.e[2] = (f16)s.z; ph.e[3] = (f16)s.w;                             \
                *(uint2*)(&Sp16[L16 * 136 + kt * 16 + quad * 4]) = ph.u2;           \
            }                                                                       \
            f32x4 accK[2], accQ[2];                                                 \
            accK[0] = (f32x4){0, 0, 0, 0}; accK[1] = (f32x4){0, 0, 0, 0};           \
            accQ[0] = (f32x4){0, 0, 0, 0}; accQ[1] = (f32x4){0, 0, 0, 0};           \
            _Pragma("unroll")                                                       \
            for (int kk = 0; kk < 4; ++kk) {                                        \
                f16x8 sf = *(const f16x8*)(&Sp16[L16 * 136 + kk * 32 + quad * 8]);  \
                _Pragma("unroll")                                                   \
                for (int nt = 0; nt < 2; ++nt) {                                    \
                    accK[nt] = __builtin_amdgcn_mfma_f32_16x16x32_f16(sf, KF[nt][kk], accK[nt], 0, 0, 0); \
                    accQ[nt] = __builtin_amdgcn_mfma_f32_16x16x32_f16(sf, QF[nt][kk], accQ[nt], 0, 0, 0); \
                }                                                                   \
            }                                                                       \
            _Pragma("unroll")                                                       \
            for (int nt = 0; nt < 2; ++nt) {                                        \
                int t = nt * 16 + L16;                                              \
                _Pragma("unroll")                                                   \
                for (int r = 0; r < 4; ++r) {                                       \
                    skv[np][(quad * 4 + r) * 34 + t] = accK[nt][r];                 \
                    sqv[np][(quad * 4 + r) * 34 + t] = accQ[nt][r];                 \
                }                                                                   \
            }                                                                       \
        }

#define DO_PREFETCH(KF, QF)                                                         \
        if (ch <= NCH - 3) {                                                        \
            int tp = (ch + 2) * SCAN_C;                                             \
            _Pragma("unroll")                                                       \
            for (int nt = 0; nt < 2; ++nt)                                          \
                _Pragma("unroll")                                                   \
                for (int kk = 0; kk < 4; ++kk) {                                    \
                    size_t g = rowbase + (size_t)(tp + nt * 16 + L16) * HIDN + kk * 32 + quad * 8; \
                    KF[nt][kk] = *(const f16x8*)(k16 + g);                          \
                    QF[nt][kk] = *(const f16x8*)(q16 + g);                          \
                }                                                                   \
        }

        for (int ch = 0; ch < NCH; ++ch) {
            const int p = ch & 1;
            const int np = p ^ 1;
            const bool haveNext = (ch + 1 < NCH);

            // (0) fire-and-forget DMA staging for next slot + early avb loads
            float4 ar0, ar1; uint4 vr; float betr = 0.f;
            if (haveNext) {
                size_t gbn = (gmatbase + ch + 1) * 1024;
                size_t gbc = (gmatbase + ch) * 1024;
                const f16* gG = G_g  + gbn + lane * 8;
                const f16* gQ = KQ_g + gbn + lane * 8;
                const f16* gX = Gx_g + gbc + lane * 8;
                const f16* gY = Qx_g + gbc + lane * 8;
                gload_lds16(gG,       &G_lds[np][0]);
                gload_lds16(gG + 512, &G_lds[np][512]);
                gload_lds16(gQ,       &Q_lds[np][0]);
                gload_lds16(gQ + 512, &Q_lds[np][512]);
                gload_lds16(gX,       &Gx_lds[np][0]);
                gload_lds16(gX + 512, &Gx_lds[np][512]);
                gload_lds16(gY,       &Qx_lds[np][0]);
                gload_lds16(gY + 512, &Qx_lds[np][512]);
                const f16* gK = KT_g + (gmatbase + ch) * 4096 + lane * 8;
#pragma unroll
                for (int i = 0; i < 8; ++i)
                    gload_lds16(gK + i * 512, &KT_lds2[np][i * 512]);
                int tn = (ch + 1) * SCAN_C;
                size_t ga = rowbase + (size_t)(tn + t_av) * HIDN + v0 + halfsel * 8;
                ar0 = *(const float4*)(a_buf + ga);
                ar1 = *(const float4*)(a_buf + ga + 4);
                vr  = *(const uint4*)(v16 + ga);
                betr = beta_buf[((size_t)(b * TLEN) + tn + t_av) * NHEAD + h];
            }

            // (1) register prefetch into the idle regset (issue EARLY)
            if ((ch & 1) == 0) { DO_PREFETCH(kfB, qfB) }
            else               { DO_PREFETCH(kfA, qfA) }

            // (2) flush o of chunk ch-1 (coalesced float4 stores, drain hidden by MM)
            if (ch >= 1) {
                const int fp = (ch - 1) & 1;
                const int tprev = (ch - 1) * SCAN_C;
                const int tt = lane >> 1;
                const int hh = (lane & 1) * 8;
                float v8[8];
#pragma unroll
                for (int j = 0; j < 8; ++j) v8[j] = o_lds[fp][hh + j][tt];
                float4 f0; f0.x = v8[0]; f0.y = v8[1]; f0.z = v8[2]; f0.w = v8[3];
                float4 f1; f1.x = v8[4]; f1.y = v8[5]; f1.z = v8[6]; f1.w = v8[7];
                size_t ob = rowbase + (size_t)(tprev + tt) * HIDN + v0 + hh;
                *(float4*)(o_buf + ob)     = f0;
                *(float4*)(o_buf + ob + 4) = f1;
            }

            // (3) state update + stale-state MM with current regset
            if ((ch & 1) == 0) { DO_UPDATE_MM(kfA, qfA) }
            else               { DO_UPDATE_MM(kfB, qfB) }

            // (4) avb LDS writes (late — loads have had the whole chunk to land)
            if (haveNext) {
                const f16* vh = (const f16*)&vr;
                const float* aa0 = (const float*)&ar0;
                const float* aa1 = (const float*)&ar1;
#pragma unroll
                for (int e = 0; e < 4; ++e) {
                    float2 wv; wv.x = aa0[e]; wv.y = betr * (float)vh[e];
                    *(float2*)(&avb[np][(halfsel * 8 + e) * 68 + 2 * t_av]) = wv;
                    float2 wu; wu.x = aa1[e]; wu.y = betr * (float)vh[4 + e];
                    *(float2*)(&avb[np][(halfsel * 8 + 4 + e) * 68 + 2 * t_av]) = wu;
                }
                if (halfsel == 0) Bts[np][t_av] = betr;
            }
            __syncthreads();
        }
#undef DO_UPDATE_MM
#undef DO_PREFETCH

        // epilogue: flush o of the last chunk
        {
            const int fp = (NCH - 1) & 1;
            const int tprev = (NCH - 1) * SCAN_C;
            const int tt = lane >> 1;
            const int hh = (lane & 1) * 8;
            float v8[8];
#pragma unroll
            for (int j = 0; j < 8; ++j) v8[j] = o_lds[fp][hh + j][tt];
            float4 f0; f0.x = v8[0]; f0.y = v8[1]; f0.z = v8[2]; f0.w = v8[3];
            float4 f1; f1.x = v8[4]; f1.y = v8[5]; f1.z = v8[6]; f1.w = v8[7];
            size_t ob = rowbase + (size_t)(tprev + tt) * HIDN + v0 + hh;
            *(float4*)(o_buf + ob)     = f0;
            *(float4*)(o_buf + ob + 4) = f1;
        }
    } else {
        // =================== WAVE 0: serial critical path ===================
        __builtin_amdgcn_s_setprio(1);
        __syncthreads();   // B1 pair

        for (int ch = 0; ch < NCH; ++ch) {
            const int p = ch & 1;
            const int np = p ^ 1;

            // ---- cross-chunk fixup: sk = P*sk_stale + c~_{ch-1} . Gx (in place) ----
            {
                f16x8 caf = *(const f16x8*)(&c16s[np][L16 * 40 + quad * 8]);
                f32x4 fK[2], fQ[2];
#pragma unroll
                for (int nt = 0; nt < 2; ++nt) {
                    f16x8 bx = *(const f16x8*)(&Gx_lds[p][(nt * 16 + L16) * 32 + quad * 8]);
                    f16x8 by = *(const f16x8*)(&Qx_lds[p][(nt * 16 + L16) * 32 + quad * 8]);
                    fK[nt] = __builtin_amdgcn_mfma_f32_16x16x32_f16(caf, bx, (f32x4){0, 0, 0, 0}, 0, 0, 0);
                    fQ[nt] = __builtin_amdgcn_mfma_f32_16x16x32_f16(caf, by, (f32x4){0, 0, 0, 0}, 0, 0, 0);
                }
#pragma unroll
                for (int r = 0; r < 4; ++r) {
                    int vv = quad * 4 + r;
                    float Pv = PCs[np][vv];
#pragma unroll
                    for (int nt = 0; nt < 2; ++nt) {
                        int t = nt * 16 + L16;
                        skv[p][vv * 34 + t] = fmaf(Pv, skv[p][vv * 34 + t], fK[nt][r]);
                        sqv[p][vv * 34 + t] = fmaf(Pv, sqv[p][vv * 34 + t], fQ[nt][r]);
                    }
                }
            }

            // ---- triangular solve: 4 windows of {bulk LDS gather -> 4 reg-only iters} ----
            {
                f16x2 c0, c1, c2, c3;
                c0.x = (f16)0.f; c0.y = (f16)0.f; c1 = c0; c2 = c0; c3 = c0;
                float P = 1.f;
                union RowU { uint4 u4; f16x2 h2[4]; };

#pragma unroll
                for (int wnd = 0; wnd < 4; ++wnd) {
                    const int tw = wnd * 8;
                    uint4  bg0[4], bg1[4], bh0[4], bh1[4];
                    float2 bskp[4], bsqp[4], bbtp[4];
                    float4 bab4[4];
                    float  bkq00[4], bg01[4];
                    f16x2  bdq[4];
#pragma unroll
                    for (int i = 0; i < 4; ++i) {
                        const int t = tw + i * 2;
                        bg0[i] = *(const uint4*)(&G_lds[p][t * 32 + li * 8]);
                        bg1[i] = *(const uint4*)(&G_lds[p][(t + 1) * 32 + li * 8]);
                        bh0[i] = *(const uint4*)(&Q_lds[p][t * 32 + li * 8]);
                        bh1[i] = *(const uint4*)(&Q_lds[p][(t + 1) * 32 + li * 8]);
                        bskp[i] = *(const float2*)(&skv[p][vl * 34 + t]);
                        bsqp[i] = *(const float2*)(&sqv[p][vl * 34 + t]);
                        bab4[i] = *(const float4*)(&avb[p][vl * 68 + 2 * t]);
                        bbtp[i] = *(const float2*)(&Bts[p][t]);
                        bkq00[i] = (float)Q_lds[p][t * 32 + t];
                        bdq[i]  = *(const f16x2*)(&Q_lds[p][(t + 1) * 32 + t]);
                        bg01[i] = (float)G_lds[p][(t + 1) * 32 + t];
                    }
#pragma unroll
                    for (int i = 0; i < 4; ++i) {
                        const int t = tw + i * 2;
                        RowU g0u, g1u, h0u, h1u;
                        g0u.u4 = bg0[i]; g1u.u4 = bg1[i];
                        h0u.u4 = bh0[i]; h1u.u4 = bh1[i];
                        float2 skp = bskp[i], sqp = bsqp[i], btp = bbtp[i];
                        float4 ab4 = bab4[i];
                        float kq00 = bkq00[i], g01 = bg01[i];
                        f16x2 dq = bdq[i];

                        float pG  = fdot2_(c0, g0u.h2[0], fdot2_(c1, g0u.h2[1], 0.f))
                                  + fdot2_(c2, g0u.h2[2], fdot2_(c3, g0u.h2[3], 0.f));
                        float pG1 = fdot2_(c0, g1u.h2[0], fdot2_(c1, g1u.h2[1], 0.f))
                                  + fdot2_(c2, g1u.h2[2], fdot2_(c3, g1u.h2[3], 0.f));
                        float pO  = fdot2_(c0, h0u.h2[0], fdot2_(c1, h0u.h2[1], 0.f))
                                  + fdot2_(c2, h0u.h2[2], fdot2_(c3, h0u.h2[3], 0.f));
                        float pO1 = fdot2_(c0, h1u.h2[0], fdot2_(c1, h1u.h2[1], 0.f))
                                  + fdot2_(c2, h1u.h2[2], fdot2_(c3, h1u.h2[3], 0.f));
                        int tmp;
                        tmp = __builtin_amdgcn_update_dpp(0, __float_as_int(pG),  0xB1, 0xF, 0xF, true); pG  += __int_as_float(tmp);
                        tmp = __builtin_amdgcn_update_dpp(0, __float_as_int(pG1), 0xB1, 0xF, 0xF, true); pG1 += __int_as_float(tmp);
                        tmp = __builtin_amdgcn_update_dpp(0, __float_as_int(pO),  0xB1, 0xF, 0xF, true); pO  += __int_as_float(tmp);
                        tmp = __builtin_amdgcn_update_dpp(0, __float_as_int(pO1), 0xB1, 0xF, 0xF, true); pO1 += __int_as_float(tmp);
                        tmp = __builtin_amdgcn_update_dpp(0, __float_as_int(pG),  0x4E, 0xF, 0xF, true); pG  += __int_as_float(tmp);
                        tmp = __builtin_amdgcn_update_dpp(0, __float_as_int(pG1), 0x4E, 0xF, 0xF, true); pG1 += __int_as_float(tmp);
                        tmp = __builtin_amdgcn_update_dpp(0, __float_as_int(pO),  0x4E, 0xF, 0xF, true); pO  += __int_as_float(tmp);
                        tmp = __builtin_amdgcn_update_dpp(0, __float_as_int(pO1), 0x4E, 0xF, 0xF, true); pO1 += __int_as_float(tmp);

                        float a0 = ab4.x, bv0 = ab4.y, a1 = ab4.z, bv1 = ab4.w;
                        float bt0 = btp.x, bt1 = btp.y;
                        float sk0 = skp.x * ISSC, sk1 = skp.y * ISSC;
                        float sq0 = sqp.x * ISSC, sq1 = sqp.y * ISSC;
                        float kq01 = (float)dq.x, kq11 = (float)dq.y;

                        // step t
                        float x0 = fmaf(P, sk0, pG);
                        float u0 = fmaf(-bt0, x0, bv0);
                        float P0 = P * a0;
                        float o0 = fmaf(a0, pO, u0 * kq00);
                        o0 = fmaf(P0, sq0, o0);
                        // step t+1 (cross-terms via u0 explicitly)
                        float accGv = fmaf(a0, pG1, u0 * g01);
                        float x1 = fmaf(P0, sk1, accGv);
                        float u1 = fmaf(-bt1, x1, bv1);
                        float P1 = P0 * a1;
                        float accOv = fmaf(a0, pO1, u0 * kq01);
                        float o1 = fmaf(a1, accOv, u1 * kq11);
                        o1 = fmaf(P1, sq1, o1);

                        float aa = a0 * a1;
                        f16 aah = (f16)aa;
                        f16x2 aa2; aa2.x = aah; aa2.y = aah;
                        c0 *= aa2; c1 *= aa2; c2 *= aa2; c3 *= aa2;
                        if (li == (t >> 3)) {
                            f16x2 un; un.x = (f16)(u0 * a1); un.y = (f16)u1;
                            int sel = (t & 7) >> 1;
                            if (sel == 0) c0 = un; else if (sel == 1) c1 = un;
                            else if (sel == 2) c2 = un; else c3 = un;
                        }
                        P = P1;
                        if (li == 0) {
                            float2 o2; o2.x = o0; o2.y = o1;
                            *(float2*)(&o_lds[p][vl][t]) = o2;
                        }
                    }
                }
                f16 s16 = (f16)SSC;
                f16x2 ss2; ss2.x = s16; ss2.y = s16;
                union { f16x2 h2[4]; uint4 u4; } pc;
                pc.h2[0] = c0 * ss2; pc.h2[1] = c1 * ss2; pc.h2[2] = c2 * ss2; pc.h2[3] = c3 * ss2;
                *(uint4*)(&c16s[p][vl * 40 + li * 8]) = pc.u4;
                if (li == 0) PCs[p][vl] = P;
            }
            __syncthreads();
        }
    }
}

// ---------------------------------------------------------------------------
// K6: LayerNorm over head dim, * g, -> f16 for output GEMM
__global__ __launch_bounds__(256) void ln_gate_kernel(
    const float* __restrict__ o_buf, const f16* __restrict__ g16,
    const float* __restrict__ lng, const float* __restrict__ lnb,
    f16* __restrict__ og16)
{
    int row = blockIdx.x;
    int h = threadIdx.x >> 5, lane = threadIdx.x & 31;
    size_t base = (size_t)row * HIDN + h * HD + lane * 4;
    float4 x = *(const float4*)(o_buf + base);
    float s  = x.x + x.y + x.z + x.w;
    float sq = x.x * x.x + x.y * x.y + x.z * x.z + x.w * x.w;
#pragma unroll
    for (int m = 1; m <= 16; m <<= 1) {
        s  += __shfl_xor(s, m);
        sq += __shfl_xor(sq, m);
    }
    float mu  = s * (1.0f / 128.0f);
    float var = sq * (1.0f / 128.0f) - mu * mu;
    float inv = 1.0f / sqrtf(var + 1e-5f);
    int d = lane * 4;
    const float* xp = (const float*)&x;
    union { f16 h4[4]; uint2 u; } pk;
#pragma unroll
    for (int j = 0; j < 4; ++j) {
        float on = (xp[j] - mu) * inv * lng[d + j] + lnb[d + j];
        pk.h4[j] = (f16)(on * (float)g16[base + j]);
    }
    *(uint2*)(og16 + base) = pk.u;
}

// ---------------------------------------------------------------------------
extern "C" void kernel_launch(void* const* d_in, const int* in_sizes, int n_in,
                              void* d_out, int out_size, void* d_ws, size_t ws_size,
                              hipStream_t stream)
{
    (void)in_sizes; (void)n_in; (void)out_size; (void)ws_size;
    const float* x   = (const float*)d_in[0];
    const float* Wq  = (const float*)d_in[1];
    const float* Wk  = (const float*)d_in[2];
    const float* Wv  = (const float*)d_in[3];
    const float* Wa  = (const float*)d_in[4];
    const float* ba  = (const float*)d_in[5];
    const float* Wb  = (const float*)d_in[6];
    const float* bb  = (const float*)d_in[7];
    const float* Wg  = (const float*)d_in[8];
    const float* Wo  = (const float*)d_in[9];
    const float* cqw = (const float*)d_in[10];
    const float* cqb = (const float*)d_in[11];
    const float* ckw = (const float*)d_in[12];
    const float* ckb = (const float*)d_in[13];
    const float* cvw = (const float*)d_in[14];
    const float* cvb = (const float*)d_in[15];
    const float* lng = (const float*)d_in[16];
    const float* lnb = (const float*)d_in[17];
    float* out = (float*)d_out;

    char* ws = (char*)d_ws;
    f16*   x16      = (f16*)(ws + 0);                 //  8,388,608 B
    f16*   WT       = (f16*)(ws + 8388608);           // 12,582,912 B
    f16*   qkvh     = (f16*)(ws + 20971520);          // 25,165,824 B (reused by gram outputs)
    f16*   qkv16    = (f16*)(ws + 46137344);          // 25,165,824 B (f16 q,k,v post-conv)
    float* a_buf    = (float*)(ws + 96468992);        // 16,777,216 B
    f16*   g16      = (f16*)(ws + 113246208);         //  8,388,608 B
    float* beta_buf = (float*)(ws + 121634816);       //    131,072 B
    float* o_buf    = (float*)(ws + 121765888);       // 16,777,216 B
    f16*   og16     = (f16*)(ws + 138543104);         //  8,388,608 B

    // gram pre-pass outputs reuse the (dead after conv) qkvh region: 16 MB <= 24 MB
    f16* G_g  = qkvh;                 // 16*64*1024 f16 = 2 MB
    f16* KQ_g = qkvh + 1048576;       // 2 MB
    f16* Gx_g = qkvh + 2097152;       // 2 MB
    f16* Qx_g = qkvh + 3145728;       // 2 MB
    f16* KT_g = qkvh + 4194304;       // 16*64*4096 f16 = 8 MB

    prep_kernel<<<dim3(14336), dim3(256), 0, stream>>>(
        x, Wq, Wk, Wv, Wa, Wg, Wo, Wb, bb, x16, WT, beta_buf);
    gemm_f16<0><<<dim3(40, 32), dim3(256), 0, stream>>>(x16, WT, nullptr, qkvh, a_buf, g16, ba);
    conv_silu_kernel<<<dim3(4096, 3), dim3(256), 0, stream>>>(qkvh, cqw, cqb, ckw, ckb, cvw, cvb, qkv16);
    gram_kernel<<<dim3(NCH, 16), dim3(64), 0, stream>>>(
        qkv16, qkv16 + XELEMS, G_g, KQ_g, Gx_g, Qx_g, KT_g);
    scan2_kernel<<<dim3(16, 8), dim3(128), 0, stream>>>(
        qkv16, qkv16 + XELEMS, qkv16 + 2 * (size_t)XELEMS, a_buf, beta_buf,
        G_g, KQ_g, Gx_g, Qx_g, KT_g, o_buf);
    ln_gate_kernel<<<dim3(4096), dim3(256), 0, stream>>>(o_buf, g16, lng, lnb, og16);
    gemm_f16<1><<<dim3(8, 32), dim3(256), 0, stream>>>(og16, WT + 5 * (size_t)MAT_ELEMS, out,
                                                       nullptr, nullptr, nullptr, nullptr);
}